// Round 13
// baseline (2641.579 us; speedup 1.0000x reference)
//
#include <hip/hip_runtime.h>
#include <hip/hip_fp16.h>
#include <math.h>

#define BSZ   384
#define BM1   383
#define DIM   256
#define NZTOT 768
#define NBLK  384
#define TPB   768
#define NITER 100
#define RINGD 8
#define ARRFULL NBLK
#define DYNB  ((8 + RINGD) * BSZ * 4)   // wpart(12288) + ring(12288) = 24576 B

// ---- ws layout (float offsets) ----
#define OFF_Z    0          // 768*256
#define OFF_NRM  196608     // 768
#define OFF_K    197376     // 384*768 fp32
#define OFF_KH   492288     // 384*384 fp16 packed (73728 floats)
#define OFF_A    639744     // 384*383 final alpha
#define OFF_NUM  786816     // NITER (pad 128)
#define OFF_DEN  786944
#define OFF_ARR  787072
#define OFF_LOSS 787200     // 2 doubles

__device__ __forceinline__ void fma4(float4& a, const float4 k, const float s) {
    a.x = fmaf(k.x, s, a.x); a.y = fmaf(k.y, s, a.y);
    a.z = fmaf(k.z, s, a.z); a.w = fmaf(k.w, s, a.w);
}

__device__ __forceinline__ float4 h4tof4(uint2 w) {
    const __half2 a = *reinterpret_cast<const __half2*>(&w.x);
    const __half2 b = *reinterpret_cast<const __half2*>(&w.y);
    const float2 fa = __half22float2(a);
    const float2 fb = __half22float2(b);
    return make_float4(fa.x, fa.y, fb.x, fb.y);
}

__global__ void init_kernel(float* num, float* den, int* arr, double* lossAcc) {
    int t = threadIdx.x;
    if (t < NITER) { num[t] = 0.f; den[t] = 0.f; arr[t] = 0; }
    if (t < 2) lossAcc[t] = 0.0;
}

__global__ void __launch_bounds__(64)
norm_kernel(const float* __restrict__ xis, const float* __restrict__ xjs,
            float* __restrict__ Z, float* __restrict__ nrm2) {
    const int row  = blockIdx.x;
    const int lane = threadIdx.x;
    const float* src = (row < BSZ) ? (xis + (size_t)row * DIM)
                                   : (xjs + (size_t)(row - BSZ) * DIM);
    float4 x = reinterpret_cast<const float4*>(src)[lane];
    float s = x.x*x.x + x.y*x.y + x.z*x.z + x.w*x.w;
    for (int m = 32; m; m >>= 1) s += __shfl_xor(s, m, 64);
    float nrm = sqrtf(s);
    float4 z;
    z.x = x.x / nrm; z.y = x.y / nrm; z.z = x.z / nrm; z.w = x.w / nrm;
    reinterpret_cast<float4*>(Z + (size_t)row * DIM)[lane] = z;
    float s2 = z.x*z.x + z.y*z.y + z.z*z.z + z.w*z.w;
    for (int m = 32; m; m >>= 1) s2 += __shfl_xor(s2, m, 64);
    if (lane == 0) nrm2[row] = s2;
}

__global__ void __launch_bounds__(256)
k_kernel(const float* __restrict__ Z, const float* __restrict__ nrm2,
         float* __restrict__ Km, __half* __restrict__ KKh) {
    const int i = blockIdx.x;
    const int j = blockIdx.y * 256 + threadIdx.x;
    __shared__ float zi[DIM];
    zi[threadIdx.x] = Z[(size_t)i * DIM + threadIdx.x];
    __syncthreads();
    const float4* zr = reinterpret_cast<const float4*>(Z + (size_t)j * DIM);
    float acc = 0.f;
    #pragma unroll 8
    for (int k = 0; k < DIM/4; ++k) {
        float4 v = zr[k];
        acc = fmaf(zi[4*k+0], v.x, acc);
        acc = fmaf(zi[4*k+1], v.y, acc);
        acc = fmaf(zi[4*k+2], v.z, acc);
        acc = fmaf(zi[4*k+3], v.w, acc);
    }
    float sq = nrm2[i] + nrm2[j] - 2.f * acc;
    sq = fmaxf(sq, 0.f);
    const float val = expf(-0.1f * sq);
    Km[(size_t)i * NZTOT + j] = val;
    if (j < BSZ) KKh[(size_t)i * BSZ + j] = __float2half(val);
}

// ---- phase-2 macros (named regs, compile-time indices; K fp16 uint2) ----
#define KLD(K0,K1,K2,K3, G) do {                                             \
    K0 = KO[((G)*4+0)*96]; K1 = KO[((G)*4+1)*96];                            \
    K2 = KO[((G)*4+2)*96]; K3 = KO[((G)*4+3)*96]; } while (0)

#define KFMA(K0,K1,K2,K3, G) do {                                            \
    const float4 zr0 = zrow4[zb4 + (G)];                                     \
    { const float4 kf = h4tof4(K0); fma4(acc0, kf, zr0.x); }                 \
    { const float4 kf = h4tof4(K1); fma4(acc0, kf, zr0.y); }                 \
    { const float4 kf = h4tof4(K2); fma4(acc0, kf, zr0.z); }                 \
    { const float4 kf = h4tof4(K3); fma4(acc0, kf, zr0.w); } } while (0)

__global__ void __launch_bounds__(TPB, 1)
pgd_kernel(const float* __restrict__ Km, const __half* __restrict__ KKh,
           const float* __restrict__ alpha_init,
           float* __restrict__ afin, float* num, float* den, int* arr) {
    const int g    = blockIdx.x;     // 0..383 : QP row b = g
    const int c    = threadIdx.x;    // 0..767
    const int lane = c & 63;
    const int wv   = c >> 6;         // 0..11
    const int o    = c / 96;         // octant: J rows [48o, 48o+48)
    const int u    = c - o * 96;     // owns cols 4u..4u+3
    const int zb4  = 12 * o;

    extern __shared__ float dynl[];
    float* const wpart = dynl;              // [8][384]
    float* const ringb = dynl + 8 * BSZ;    // [RINGD][384]

    __shared__ float4 zrow4[98];
    __shared__ float  rscr[12][4];   // per-wave: zn, kb*zn, nump, an2
    __shared__ float  SD[2];         // S, D
    __shared__ unsigned long long scanm[2];

    const bool act = (c < BSZ);

    // ---- per-column init (diagonal thread c==g inert) ----
    const bool vld = act && (c != g);
    const float kb = act ? Km[(size_t)g * NZTOT + c] : 0.f;
    float a = 0.f;
    if (vld) {
        const int i = c - (c > g ? 1 : 0);
        a = alpha_init[(size_t)g * BM1 + i];
        a = fminf(fmaxf(a, 0.f), 1.f);
    }

    const uint2* __restrict__ KO = reinterpret_cast<const uint2*>(KKh)
                                   + (size_t)(48 * o) * 96 + u;

    // ---- prologue "phase 3" for t=0: z(0)=a, reductions ----
    {
        if (act) ((float*)&zrow4[0])[c] = a;
        float vv[4] = { a, kb * a, 0.f, a * a };
        #pragma unroll
        for (int k = 0; k < 4; ++k) {
            float x = vv[k];
            x += __shfl_down(x, 32, 64); x += __shfl_down(x, 16, 64);
            x += __shfl_down(x,  8, 64); x += __shfl_down(x,  4, 64);
            x += __shfl_down(x,  2, 64); x += __shfl_down(x,  1, 64);
            if (lane == 0) rscr[wv][k] = x;
        }
        if (c < 2) scanm[c] = 0ULL;
    }
    __syncthreads();

    int stopT = -1;
    int sstate = 0, okv = 0, aval = 0;
    float nnv = 0.f, ddv = 1.f;

    for (int t = 0; t < NITER; ++t) {
        // ---- top: stop decision (from ballots of t-1) ----
        {
            const unsigned long long m0 = scanm[0], m1 = scanm[1];
            const int st = m0 ? (__ffsll(m0) - 1) : (m1 ? 63 + __ffsll(m1) : -1);
            if (st >= 0) { stopT = st; break; }
        }
        if (c < 2) {
            float s = 0.f;
            #pragma unroll
            for (int w = 0; w < 12; ++w) s += rscr[w][c];
            SD[c] = s;
        }
        // ---- fire-and-forget publish of iteration t-1 (c==0) ----
        if (c == 0) {
            float nb = 0.f, db = 0.f;
            #pragma unroll
            for (int w = 0; w < 12; ++w) { nb += rscr[w][2]; db += rscr[w][3]; }
            __hip_atomic_fetch_add(&den[t], db, __ATOMIC_RELAXED, __HIP_MEMORY_SCOPE_AGENT);
            if (t > 0) {
                __hip_atomic_fetch_add(&num[t - 1], nb, __ATOMIC_RELAXED, __HIP_MEMORY_SCOPE_AGENT);
                __hip_atomic_fetch_add(&arr[t - 1], 1, __ATOMIC_RELEASE, __HIP_MEMORY_SCOPE_AGENT);
            }
        }
        // ---- scan loads (state machine; evaluated in phase 3) ----
        if (c < NITER) {
            if (sstate == 0) {
                aval = __hip_atomic_load(&arr[c], __ATOMIC_RELAXED, __HIP_MEMORY_SCOPE_AGENT);
            } else if (sstate == 1) {
                nnv = __hip_atomic_load(&num[c], __ATOMIC_RELAXED, __HIP_MEMORY_SCOPE_AGENT);
                ddv = __hip_atomic_load(&den[c], __ATOMIC_RELAXED, __HIP_MEMORY_SCOPE_AGENT);
            }
        }

        // ---- phase 2: octant matvec (fp16 K), 12 groups, depth-3 pipeline ----
        float4 acc0 = make_float4(0.f,0.f,0.f,0.f);
        {
            uint2 kA0,kA1,kA2,kA3, kB0,kB1,kB2,kB3, kC0,kC1,kC2,kC3;
            KLD(kA0,kA1,kA2,kA3, 0);
            KLD(kB0,kB1,kB2,kB3, 1);
            KLD(kC0,kC1,kC2,kC3, 2);  KFMA(kA0,kA1,kA2,kA3, 0);
            KLD(kA0,kA1,kA2,kA3, 3);  KFMA(kB0,kB1,kB2,kB3, 1);
            KLD(kB0,kB1,kB2,kB3, 4);  KFMA(kC0,kC1,kC2,kC3, 2);
            KLD(kC0,kC1,kC2,kC3, 5);  KFMA(kA0,kA1,kA2,kA3, 3);
            KLD(kA0,kA1,kA2,kA3, 6);  KFMA(kB0,kB1,kB2,kB3, 4);
            KLD(kB0,kB1,kB2,kB3, 7);  KFMA(kC0,kC1,kC2,kC3, 5);
            KLD(kC0,kC1,kC2,kC3, 8);  KFMA(kA0,kA1,kA2,kA3, 6);
            KLD(kA0,kA1,kA2,kA3, 9);  KFMA(kB0,kB1,kB2,kB3, 7);
            KLD(kB0,kB1,kB2,kB3, 10); KFMA(kC0,kC1,kC2,kC3, 8);
            KLD(kC0,kC1,kC2,kC3, 11); KFMA(kA0,kA1,kA2,kA3, 9);
            KFMA(kB0,kB1,kB2,kB3, 10);
            KFMA(kC0,kC1,kC2,kC3, 11);
        }
        *reinterpret_cast<float4*>(&wpart[o * BSZ + 4*u]) = acc0;
        __syncthreads();   // B2

        // ---- phase 3: step t, prepare t+1, reductions, scan eval ----
        float nump = 0.f, an2 = 0.f, zn = 0.f;
        if (act) {
            const int slot = t & (RINGD - 1);
            const float beta1 = (float)(t + 1) / ((float)(t + 1) + 3.0f);
            float w = 0.f;
            #pragma unroll
            for (int oo = 0; oo < 8; ++oo) w += wpart[oo * BSZ + c];
            const float z = ((const float*)&zrow4[0])[c];
            float an = 0.f;
            if (vld) {
                const float grad = SD[0] * (1.f - kb) + 0.1f * z + w - SD[1] - 2.0f;
                an = z - 0.001f * grad;
                an = fminf(fmaxf(an, 0.f), 1.f);
            }
            const float d = an - a;
            nump = d * d;
            an2  = an * an;
            zn   = an + beta1 * (an - a);
            ringb[(size_t)slot * BSZ + c] = an;
            a = an;
            ((float*)&zrow4[0])[c] = zn;
        }
        {
            float vv[4] = { zn, kb * zn, nump, an2 };
            #pragma unroll
            for (int k = 0; k < 4; ++k) {
                float x = vv[k];
                x += __shfl_down(x, 32, 64); x += __shfl_down(x, 16, 64);
                x += __shfl_down(x,  8, 64); x += __shfl_down(x,  4, 64);
                x += __shfl_down(x,  2, 64); x += __shfl_down(x,  1, 64);
                if (lane == 0) rscr[wv][k] = x;
            }
        }
        // ---- scan state transitions + ballot ----
        if (c < NITER) {
            if (sstate == 0) { if (aval == ARRFULL) sstate = 1; }
            else if (sstate == 1) {
                okv = (sqrtf(nnv) / (sqrtf(ddv) + 1e-8f) < 0.01f) ? 1 : 0;
                sstate = 2;
            }
        }
        {
            const unsigned long long bm = __ballot(okv);
            if (lane == 0 && wv < 2) scanm[wv] = bm;
        }
        __syncthreads();   // B3
    }

    // ---- finalize ----
    if (vld) {
        const float av = (stopT >= 0)
            ? ringb[(size_t)(stopT & (RINGD - 1)) * BSZ + c]
            : a;
        const int i = c - (c > g ? 1 : 0);
        afin[(size_t)g * BM1 + i] = av;
    }
}

__global__ void __launch_bounds__(384)
loss_kernel(const float* __restrict__ Km, const float* __restrict__ afin,
            double* lossAcc) {
    const int b    = blockIdx.x;
    const int tid  = threadIdx.x;
    const int lane = tid & 63;
    const int wv   = tid >> 6;
    __shared__ double dscr[6][2];
    double np = 0.0, pp = 0.0;
    if (tid < BM1) {
        const float ay = afin[(size_t)b * BM1 + tid];
        const int   I  = tid + (tid >= b);
        np = (double)ay * (double)Km[(size_t)I * NZTOT + BSZ + b];
        pp = (double)ay * (double)Km[(size_t)b * NZTOT + BSZ + b];
    }
    for (int o = 32; o; o >>= 1) { np += __shfl_down(np, o, 64); pp += __shfl_down(pp, o, 64); }
    if (lane == 0) { dscr[wv][0] = np; dscr[wv][1] = pp; }
    __syncthreads();
    if (tid == 0) {
        double nb = 0.0, pb = 0.0;
        for (int w = 0; w < 6; ++w) { nb += dscr[w][0]; pb += dscr[w][1]; }
        __hip_atomic_fetch_add(&lossAcc[0], nb, __ATOMIC_RELAXED, __HIP_MEMORY_SCOPE_AGENT);
        __hip_atomic_fetch_add(&lossAcc[1], pb, __ATOMIC_RELAXED, __HIP_MEMORY_SCOPE_AGENT);
    }
}

__global__ void fin_kernel(const double* lossAcc, float* out) {
    out[0] = expf((float)(lossAcc[0] / 384.0 - lossAcc[1] / 384.0));
}

extern "C" void kernel_launch(void* const* d_in, const int* in_sizes, int n_in,
                              void* d_out, int out_size, void* d_ws, size_t ws_size,
                              hipStream_t stream) {
    const float* xis        = (const float*)d_in[0];
    const float* xjs        = (const float*)d_in[1];
    const float* alpha_init = (const float*)d_in[2];
    float* ws   = (float*)d_ws;
    float* Z    = ws + OFF_Z;
    float* nrm2 = ws + OFF_NRM;
    float* Km   = ws + OFF_K;
    __half* KKh = (__half*)(ws + OFF_KH);
    float* afin = ws + OFF_A;
    float* num  = ws + OFF_NUM;
    float* den  = ws + OFF_DEN;
    int*   arr  = (int*)(ws + OFF_ARR);
    double* lossAcc = (double*)(ws + OFF_LOSS);
    float* out  = (float*)d_out;

    hipFuncSetAttribute((const void*)pgd_kernel,
                        hipFuncAttributeMaxDynamicSharedMemorySize, DYNB);

    hipLaunchKernelGGL(init_kernel, dim3(1), dim3(128), 0, stream, num, den, arr, lossAcc);
    hipLaunchKernelGGL(norm_kernel, dim3(NZTOT), dim3(64), 0, stream, xis, xjs, Z, nrm2);
    hipLaunchKernelGGL(k_kernel, dim3(BSZ, 3), dim3(256), 0, stream, Z, nrm2, Km, KKh);
    hipLaunchKernelGGL(pgd_kernel, dim3(NBLK), dim3(TPB), DYNB, stream,
                       Km, KKh, alpha_init, afin, num, den, arr);
    hipLaunchKernelGGL(loss_kernel, dim3(BSZ), dim3(384), 0, stream, Km, afin, lossAcc);
    hipLaunchKernelGGL(fin_kernel, dim3(1), dim3(1), 0, stream, lossAcc, out);
}

// Round 14
// 960.298 us; speedup vs baseline: 2.7508x; 2.7508x over previous
//
#include <hip/hip_runtime.h>
#include <hip/hip_fp16.h>
#include <math.h>

#define BSZ   384
#define BM1   383
#define DIM   256
#define NZTOT 768
#define NBLK  96
#define RPB   4
#define TPB   768
#define NITER 100
#define RINGD 8
#define ARRFULL NBLK
#define KRESB 73728                      // 96 rows fp16 packed in LDS
#define WPARTB (8 * RPB * BSZ * 4)       // 49152
#define DYNB  (KRESB + WPARTB)           // 122880

// ---- ws layout (float offsets) ----
#define OFF_Z    0          // 768*256
#define OFF_NRM  196608     // 768
#define OFF_K    197376     // 384*768 fp32
#define OFF_KH   492288     // 384*384 fp16 row-pair packed (36864 floats)
#define OFF_A    639744     // 384*383 final alpha
#define OFF_NUM  786816     // NITER (pad 128)
#define OFF_DEN  786944
#define OFF_ARR  787072
#define OFF_LOSS 787200     // 2 doubles

__device__ __forceinline__ float2 h2f(unsigned int w) {
    return __half22float2(*reinterpret_cast<const __half2*>(&w));
}

__global__ void init_kernel(float* num, float* den, int* arr, double* lossAcc) {
    int t = threadIdx.x;
    if (t < NITER) { num[t] = 0.f; den[t] = 0.f; arr[t] = 0; }
    if (t < 2) lossAcc[t] = 0.0;
}

__global__ void __launch_bounds__(64)
norm_kernel(const float* __restrict__ xis, const float* __restrict__ xjs,
            float* __restrict__ Z, float* __restrict__ nrm2) {
    const int row  = blockIdx.x;
    const int lane = threadIdx.x;
    const float* src = (row < BSZ) ? (xis + (size_t)row * DIM)
                                   : (xjs + (size_t)(row - BSZ) * DIM);
    float4 x = reinterpret_cast<const float4*>(src)[lane];
    float s = x.x*x.x + x.y*x.y + x.z*x.z + x.w*x.w;
    for (int m = 32; m; m >>= 1) s += __shfl_xor(s, m, 64);
    float nrm = sqrtf(s);
    float4 z;
    z.x = x.x / nrm; z.y = x.y / nrm; z.z = x.z / nrm; z.w = x.w / nrm;
    reinterpret_cast<float4*>(Z + (size_t)row * DIM)[lane] = z;
    float s2 = z.x*z.x + z.y*z.y + z.z*z.z + z.w*z.w;
    for (int m = 32; m; m >>= 1) s2 += __shfl_xor(s2, m, 64);
    if (lane == 0) nrm2[row] = s2;
}

__global__ void __launch_bounds__(256)
k_kernel(const float* __restrict__ Z, const float* __restrict__ nrm2,
         float* __restrict__ Km, __half* __restrict__ KP2) {
    const int i = blockIdx.x;
    const int j = blockIdx.y * 256 + threadIdx.x;
    __shared__ float zi[DIM];
    zi[threadIdx.x] = Z[(size_t)i * DIM + threadIdx.x];
    __syncthreads();
    const float4* zr = reinterpret_cast<const float4*>(Z + (size_t)j * DIM);
    float acc = 0.f;
    #pragma unroll 8
    for (int k = 0; k < DIM/4; ++k) {
        float4 v = zr[k];
        acc = fmaf(zi[4*k+0], v.x, acc);
        acc = fmaf(zi[4*k+1], v.y, acc);
        acc = fmaf(zi[4*k+2], v.z, acc);
        acc = fmaf(zi[4*k+3], v.w, acc);
    }
    float sq = nrm2[i] + nrm2[j] - 2.f * acc;
    sq = fmaxf(sq, 0.f);
    const float val = expf(-0.1f * sq);
    Km[(size_t)i * NZTOT + j] = val;
    // row-pair packed: KP2[(i/2)*768 + j*2 + (i&1)]
    if (j < BSZ) KP2[(size_t)(i >> 1) * 768 + j * 2 + (i & 1)] = __float2half(val);
}

// ---- phase-2 macros (named regs, compile-time indices) ----
#define KLDG(KA, KB, G) do {                                                  \
    KA = *reinterpret_cast<const uint4*>(kp2b + (size_t)(24*o + 2*(G))*1536 + 16*u);        \
    KB = *reinterpret_cast<const uint4*>(kp2b + (size_t)(24*o + 2*(G))*1536 + 1536 + 16*u); \
} while (0)

#define KRES(KA, KB, G) do {                                                  \
    KA = *reinterpret_cast<const uint4*>(kresb + ((o*3 + (G))*3072) + 16*u);          \
    KB = *reinterpret_cast<const uint4*>(kresb + ((o*3 + (G))*3072) + 1536 + 16*u);   \
} while (0)

#define COLF(comp, KAc, KBc) do {                                             \
    const float2 _fa = h2f(KAc); const float2 _fb = h2f(KBc);                 \
    acc0.comp = fmaf(_fa.x, _z0.x, acc0.comp); acc0.comp = fmaf(_fa.y, _z0.y, acc0.comp); \
    acc0.comp = fmaf(_fb.x, _z0.z, acc0.comp); acc0.comp = fmaf(_fb.y, _z0.w, acc0.comp); \
    acc1.comp = fmaf(_fa.x, _z1.x, acc1.comp); acc1.comp = fmaf(_fa.y, _z1.y, acc1.comp); \
    acc1.comp = fmaf(_fb.x, _z1.z, acc1.comp); acc1.comp = fmaf(_fb.y, _z1.w, acc1.comp); \
    acc2.comp = fmaf(_fa.x, _z2.x, acc2.comp); acc2.comp = fmaf(_fa.y, _z2.y, acc2.comp); \
    acc2.comp = fmaf(_fb.x, _z2.z, acc2.comp); acc2.comp = fmaf(_fb.y, _z2.w, acc2.comp); \
    acc3.comp = fmaf(_fa.x, _z3.x, acc3.comp); acc3.comp = fmaf(_fa.y, _z3.y, acc3.comp); \
    acc3.comp = fmaf(_fb.x, _z3.z, acc3.comp); acc3.comp = fmaf(_fb.y, _z3.w, acc3.comp); \
} while (0)

#define GFMA(KA, KB, G) do {                                                  \
    const float4 _z0 = zrow4[0][zb4 + (G)];                                   \
    const float4 _z1 = zrow4[1][zb4 + (G)];                                   \
    const float4 _z2 = zrow4[2][zb4 + (G)];                                   \
    const float4 _z3 = zrow4[3][zb4 + (G)];                                   \
    COLF(x, (KA).x, (KB).x);                                                  \
    COLF(y, (KA).y, (KB).y);                                                  \
    COLF(z, (KA).z, (KB).z);                                                  \
    COLF(w, (KA).w, (KB).w);                                                  \
} while (0)

__global__ void __launch_bounds__(TPB, 1)
pgd_kernel(const float* __restrict__ Km, const __half* __restrict__ KP2,
           const float* __restrict__ alpha_init,
           float* __restrict__ afin, float* num, float* den, int* arr) {
    const int g    = blockIdx.x;     // 0..95
    const int c    = threadIdx.x;    // 0..767
    const int lane = c & 63;
    const int wv   = c >> 6;         // 0..11
    const int o    = c / 96;         // octant: rows [48o, 48o+48)
    const int u    = c - o * 96;     // owns cols 4u..4u+3
    const int zb4  = 12 * o;

    extern __shared__ char dynlc[];
    char* const  kresb = dynlc;                       // 96 rows fp16 packed
    float* const wpart = (float*)(dynlc + KRESB);     // [8][RPB][384]

    __shared__ float4 zrow4[RPB][98];
    __shared__ float  rscr[12][10];   // per-wave: zn0..3, kbzn0..3, nump, an2
    __shared__ float  SD[8];          // S0..3, D0..3
    __shared__ unsigned long long scanm[2];

    const bool act = (c < BSZ);
    const char* const kp2b = (const char*)KP2;

    // ---- per-row init (diagonal thread c==b inert) ----
    float a[RPB], kb[RPB]; bool vld[RPB];
    #pragma unroll
    for (int r = 0; r < RPB; ++r) {
        const int b = g * RPB + r;
        vld[r] = act && (c != b);
        kb[r]  = act ? Km[(size_t)b * NZTOT + c] : 0.f;
        float v = 0.f;
        if (vld[r]) {
            const int i = c - (c > b ? 1 : 0);
            v = alpha_init[(size_t)b * BM1 + i];
            v = fminf(fmaxf(v, 0.f), 1.f);
        }
        a[r] = v;
    }

    // ---- packed-fp16 register ring ----
    unsigned histx[RINGD], histy[RINGD];
    {
        const __half2 h01 = __floats2half2_rn(a[0], a[1]);
        const __half2 h23 = __floats2half2_rn(a[2], a[3]);
        const unsigned px = *reinterpret_cast<const unsigned*>(&h01);
        const unsigned py = *reinterpret_cast<const unsigned*>(&h23);
        #pragma unroll
        for (int s = 0; s < RINGD; ++s) { histx[s] = px; histy[s] = py; }
    }

    // ---- prologue: copy resident granules (0..2 of each octant) into LDS ----
    #pragma unroll
    for (int G = 0; G < 3; ++G) {
        const uint4 va = *reinterpret_cast<const uint4*>(kp2b + (size_t)(24*o + 2*G)*1536 + 16*u);
        const uint4 vb = *reinterpret_cast<const uint4*>(kp2b + (size_t)(24*o + 2*G)*1536 + 1536 + 16*u);
        *reinterpret_cast<uint4*>(kresb + (o*3 + G)*3072 + 16*u)        = va;
        *reinterpret_cast<uint4*>(kresb + (o*3 + G)*3072 + 1536 + 16*u) = vb;
    }

    // ---- prologue "phase 3" for t=0: z(0)=a, reductions ----
    {
        float an2 = 0.f;
        float vv[10];
        #pragma unroll
        for (int r = 0; r < RPB; ++r) {
            if (act) ((float*)&zrow4[r][0])[c] = a[r];
            vv[r]     = a[r];
            vv[4 + r] = kb[r] * a[r];
            an2 += a[r] * a[r];
        }
        vv[8] = 0.f; vv[9] = an2;
        #pragma unroll
        for (int k = 0; k < 10; ++k) {
            float x = vv[k];
            x += __shfl_down(x, 32, 64); x += __shfl_down(x, 16, 64);
            x += __shfl_down(x,  8, 64); x += __shfl_down(x,  4, 64);
            x += __shfl_down(x,  2, 64); x += __shfl_down(x,  1, 64);
            if (lane == 0) rscr[wv][k] = x;
        }
        if (c < 2) scanm[c] = 0ULL;
    }
    __syncthreads();

    int stopT = -1;
    int sstate = 0, okv = 0, aval = 0;
    float nnv = 0.f, ddv = 1.f;

    for (int t = 0; t < NITER; ++t) {
        // ---- top: stop decision (from ballots of t-1) ----
        {
            const unsigned long long m0 = scanm[0], m1 = scanm[1];
            const int st = m0 ? (__ffsll(m0) - 1) : (m1 ? 63 + __ffsll(m1) : -1);
            if (st >= 0) { stopT = st; break; }
        }
        if (c < 8) {
            float s = 0.f;
            #pragma unroll
            for (int w = 0; w < 12; ++w) s += rscr[w][c];
            SD[c] = s;
        }
        // ---- fire-and-forget publish of iteration t-1 (c==0) ----
        if (c == 0) {
            float nb = 0.f, db = 0.f;
            #pragma unroll
            for (int w = 0; w < 12; ++w) { nb += rscr[w][8]; db += rscr[w][9]; }
            __hip_atomic_fetch_add(&den[t], db, __ATOMIC_RELAXED, __HIP_MEMORY_SCOPE_AGENT);
            if (t > 0) {
                __hip_atomic_fetch_add(&num[t - 1], nb, __ATOMIC_RELAXED, __HIP_MEMORY_SCOPE_AGENT);
                __hip_atomic_fetch_add(&arr[t - 1], 1, __ATOMIC_RELEASE, __HIP_MEMORY_SCOPE_AGENT);
            }
        }
        // ---- scan loads (state machine; evaluated in phase 3) ----
        if (c < NITER) {
            if (sstate == 0) {
                aval = __hip_atomic_load(&arr[c], __ATOMIC_RELAXED, __HIP_MEMORY_SCOPE_AGENT);
            } else if (sstate == 1) {
                nnv = __hip_atomic_load(&num[c], __ATOMIC_RELAXED, __HIP_MEMORY_SCOPE_AGENT);
                ddv = __hip_atomic_load(&den[c], __ATOMIC_RELAXED, __HIP_MEMORY_SCOPE_AGENT);
            }
        }

        // ---- phase 2: octant matvec: 3 LDS granules + 9 streamed (uint4) ----
        float4 acc0 = make_float4(0.f,0.f,0.f,0.f);
        float4 acc1 = make_float4(0.f,0.f,0.f,0.f);
        float4 acc2 = make_float4(0.f,0.f,0.f,0.f);
        float4 acc3 = make_float4(0.f,0.f,0.f,0.f);
        {
            uint4 kA0,kA1, kB0,kB1, kC0,kC1;
            KLDG(kA0,kA1, 3);
            KLDG(kB0,kB1, 4);
            { uint4 r0,r1; KRES(r0,r1, 0); GFMA(r0,r1, 0); }
            KLDG(kC0,kC1, 5);
            { uint4 r0,r1; KRES(r0,r1, 1); GFMA(r0,r1, 1); }
            { uint4 r0,r1; KRES(r0,r1, 2); GFMA(r0,r1, 2); }
            GFMA(kA0,kA1, 3);  KLDG(kA0,kA1, 6);
            GFMA(kB0,kB1, 4);  KLDG(kB0,kB1, 7);
            GFMA(kC0,kC1, 5);  KLDG(kC0,kC1, 8);
            GFMA(kA0,kA1, 6);  KLDG(kA0,kA1, 9);
            GFMA(kB0,kB1, 7);  KLDG(kB0,kB1, 10);
            GFMA(kC0,kC1, 8);  KLDG(kC0,kC1, 11);
            GFMA(kA0,kA1, 9);
            GFMA(kB0,kB1, 10);
            GFMA(kC0,kC1, 11);
        }
        *reinterpret_cast<float4*>(&wpart[(o * RPB + 0) * BSZ + 4*u]) = acc0;
        *reinterpret_cast<float4*>(&wpart[(o * RPB + 1) * BSZ + 4*u]) = acc1;
        *reinterpret_cast<float4*>(&wpart[(o * RPB + 2) * BSZ + 4*u]) = acc2;
        *reinterpret_cast<float4*>(&wpart[(o * RPB + 3) * BSZ + 4*u]) = acc3;
        __syncthreads();   // B2

        // ---- phase 3: step t, prepare t+1, reductions, scan eval ----
        float nump = 0.f, an2 = 0.f;
        float zn[RPB] = {0.f, 0.f, 0.f, 0.f};
        float anA[RPB] = {0.f, 0.f, 0.f, 0.f};
        if (act) {
            const float beta1 = (float)(t + 1) / ((float)(t + 1) + 3.0f);
            #pragma unroll
            for (int r = 0; r < RPB; ++r) {
                float w = 0.f;
                #pragma unroll
                for (int oo = 0; oo < 8; ++oo) w += wpart[(oo * RPB + r) * BSZ + c];
                const float z = ((const float*)&zrow4[r][0])[c];
                float an = 0.f;
                if (vld[r]) {
                    const float grad = SD[r] * (1.f - kb[r]) + 0.1f * z + w - SD[4 + r] - 2.0f;
                    an = z - 0.001f * grad;
                    an = fminf(fmaxf(an, 0.f), 1.f);
                }
                const float d = an - a[r];
                nump += d * d;
                an2  += an * an;
                zn[r] = an + beta1 * (an - a[r]);
                anA[r] = an;
                a[r] = an;
            }
            #pragma unroll
            for (int r = 0; r < RPB; ++r) ((float*)&zrow4[r][0])[c] = zn[r];
        }
        // ---- packed-fp16 register ring update ----
        {
            const int slot = t & (RINGD - 1);
            const __half2 h01 = __floats2half2_rn(anA[0], anA[1]);
            const __half2 h23 = __floats2half2_rn(anA[2], anA[3]);
            const unsigned px = *reinterpret_cast<const unsigned*>(&h01);
            const unsigned py = *reinterpret_cast<const unsigned*>(&h23);
            #pragma unroll
            for (int s2 = 0; s2 < RINGD; ++s2) {
                histx[s2] = (s2 == slot) ? px : histx[s2];
                histy[s2] = (s2 == slot) ? py : histy[s2];
            }
        }
        {
            float vv[10] = { zn[0], zn[1], zn[2], zn[3],
                             kb[0]*zn[0], kb[1]*zn[1], kb[2]*zn[2], kb[3]*zn[3],
                             nump, an2 };
            #pragma unroll
            for (int k = 0; k < 10; ++k) {
                float x = vv[k];
                x += __shfl_down(x, 32, 64); x += __shfl_down(x, 16, 64);
                x += __shfl_down(x,  8, 64); x += __shfl_down(x,  4, 64);
                x += __shfl_down(x,  2, 64); x += __shfl_down(x,  1, 64);
                if (lane == 0) rscr[wv][k] = x;
            }
        }
        // ---- scan state transitions + ballot ----
        if (c < NITER) {
            if (sstate == 0) { if (aval == ARRFULL) sstate = 1; }
            else if (sstate == 1) {
                okv = (sqrtf(nnv) / (sqrtf(ddv) + 1e-8f) < 0.01f) ? 1 : 0;
                sstate = 2;
            }
        }
        {
            const unsigned long long bm = __ballot(okv);
            if (lane == 0 && wv < 2) scanm[wv] = bm;
        }
        __syncthreads();   // B3
    }

    // ---- finalize ----
    float av[RPB];
    #pragma unroll
    for (int r = 0; r < RPB; ++r) av[r] = a[r];
    if (stopT >= 0) {
        unsigned sx = histx[0], sy = histy[0];
        const int sl = stopT & (RINGD - 1);
        #pragma unroll
        for (int s2 = 0; s2 < RINGD; ++s2) {
            sx = (s2 == sl) ? histx[s2] : sx;
            sy = (s2 == sl) ? histy[s2] : sy;
        }
        const float2 f01 = __half22float2(*reinterpret_cast<const __half2*>(&sx));
        const float2 f23 = __half22float2(*reinterpret_cast<const __half2*>(&sy));
        av[0] = f01.x; av[1] = f01.y; av[2] = f23.x; av[3] = f23.y;
    }
    if (act) {
        #pragma unroll
        for (int r = 0; r < RPB; ++r) {
            const int b = g * RPB + r;
            if (vld[r]) {
                const int i = c - (c > b ? 1 : 0);
                afin[(size_t)b * BM1 + i] = av[r];
            }
        }
    }
}

__global__ void __launch_bounds__(384)
loss_kernel(const float* __restrict__ Km, const float* __restrict__ afin,
            double* lossAcc) {
    const int b    = blockIdx.x;
    const int tid  = threadIdx.x;
    const int lane = tid & 63;
    const int wv   = tid >> 6;
    __shared__ double dscr[6][2];
    double np = 0.0, pp = 0.0;
    if (tid < BM1) {
        const float ay = afin[(size_t)b * BM1 + tid];
        const int   I  = tid + (tid >= b);
        np = (double)ay * (double)Km[(size_t)I * NZTOT + BSZ + b];
        pp = (double)ay * (double)Km[(size_t)b * NZTOT + BSZ + b];
    }
    for (int o = 32; o; o >>= 1) { np += __shfl_down(np, o, 64); pp += __shfl_down(pp, o, 64); }
    if (lane == 0) { dscr[wv][0] = np; dscr[wv][1] = pp; }
    __syncthreads();
    if (tid == 0) {
        double nb = 0.0, pb = 0.0;
        for (int w = 0; w < 6; ++w) { nb += dscr[w][0]; pb += dscr[w][1]; }
        __hip_atomic_fetch_add(&lossAcc[0], nb, __ATOMIC_RELAXED, __HIP_MEMORY_SCOPE_AGENT);
        __hip_atomic_fetch_add(&lossAcc[1], pb, __ATOMIC_RELAXED, __HIP_MEMORY_SCOPE_AGENT);
    }
}

__global__ void fin_kernel(const double* lossAcc, float* out) {
    out[0] = expf((float)(lossAcc[0] / 384.0 - lossAcc[1] / 384.0));
}

extern "C" void kernel_launch(void* const* d_in, const int* in_sizes, int n_in,
                              void* d_out, int out_size, void* d_ws, size_t ws_size,
                              hipStream_t stream) {
    const float* xis        = (const float*)d_in[0];
    const float* xjs        = (const float*)d_in[1];
    const float* alpha_init = (const float*)d_in[2];
    float* ws   = (float*)d_ws;
    float* Z    = ws + OFF_Z;
    float* nrm2 = ws + OFF_NRM;
    float* Km   = ws + OFF_K;
    __half* KP2 = (__half*)(ws + OFF_KH);
    float* afin = ws + OFF_A;
    float* num  = ws + OFF_NUM;
    float* den  = ws + OFF_DEN;
    int*   arr  = (int*)(ws + OFF_ARR);
    double* lossAcc = (double*)(ws + OFF_LOSS);
    float* out  = (float*)d_out;

    hipFuncSetAttribute((const void*)pgd_kernel,
                        hipFuncAttributeMaxDynamicSharedMemorySize, DYNB);

    hipLaunchKernelGGL(init_kernel, dim3(1), dim3(128), 0, stream, num, den, arr, lossAcc);
    hipLaunchKernelGGL(norm_kernel, dim3(NZTOT), dim3(64), 0, stream, xis, xjs, Z, nrm2);
    hipLaunchKernelGGL(k_kernel, dim3(BSZ, 3), dim3(256), 0, stream, Z, nrm2, Km, KP2);
    hipLaunchKernelGGL(pgd_kernel, dim3(NBLK), dim3(TPB), DYNB, stream,
                       Km, KP2, alpha_init, afin, num, den, arr);
    hipLaunchKernelGGL(loss_kernel, dim3(BSZ), dim3(384), 0, stream, Km, afin, lossAcc);
    hipLaunchKernelGGL(fin_kernel, dim3(1), dim3(1), 0, stream, lossAcc, out);
}

// Round 15
// 828.412 us; speedup vs baseline: 3.1887x; 1.1592x over previous
//
#include <hip/hip_runtime.h>
#include <hip/hip_fp16.h>
#include <math.h>

#define BSZ   384
#define BM1   383
#define DIM   256
#define NZTOT 768
#define NBLK  96
#define RPB   4
#define TPB   768
#define NITER 100
#define RINGD 8
#define ARRFULL NBLK
#define KRESB 98304                      // 128 rows fp16 packed in LDS (4 granules/octant)
#define WPARTB (8 * RPB * BSZ * 4)       // 49152
#define DYNB  (KRESB + WPARTB)           // 147456

// ---- ws layout (float offsets) ----
#define OFF_Z    0          // 768*256
#define OFF_NRM  196608     // 768
#define OFF_K    197376     // 384*768 fp32
#define OFF_KH   492288     // 384*384 fp16 row-pair packed (36864 floats)
#define OFF_A    639744     // 384*383 final alpha
#define OFF_NUM  786816     // NITER (pad 128)
#define OFF_DEN  786944
#define OFF_ARR  787072
#define OFF_LOSS 787200     // 2 doubles

__device__ __forceinline__ float2 h2f(unsigned int w) {
    return __half22float2(*reinterpret_cast<const __half2*>(&w));
}

__device__ __forceinline__ float dot2u(unsigned k, unsigned z, float acc) {
#if defined(__has_builtin) && __has_builtin(__builtin_amdgcn_fdot2)
    typedef _Float16 h2t __attribute__((ext_vector_type(2)));
    union { unsigned u; h2t h; } uk, uz;
    uk.u = k; uz.u = z;
    return __builtin_amdgcn_fdot2(uk.h, uz.h, acc, false);
#else
    const float2 fk = h2f(k); const float2 fz = h2f(z);
    return fmaf(fk.y, fz.y, fmaf(fk.x, fz.x, acc));
#endif
}

__global__ void init_kernel(float* num, float* den, int* arr, double* lossAcc) {
    int t = threadIdx.x;
    if (t < NITER) { num[t] = 0.f; den[t] = 0.f; arr[t] = 0; }
    if (t < 2) lossAcc[t] = 0.0;
}

__global__ void __launch_bounds__(64)
norm_kernel(const float* __restrict__ xis, const float* __restrict__ xjs,
            float* __restrict__ Z, float* __restrict__ nrm2) {
    const int row  = blockIdx.x;
    const int lane = threadIdx.x;
    const float* src = (row < BSZ) ? (xis + (size_t)row * DIM)
                                   : (xjs + (size_t)(row - BSZ) * DIM);
    float4 x = reinterpret_cast<const float4*>(src)[lane];
    float s = x.x*x.x + x.y*x.y + x.z*x.z + x.w*x.w;
    for (int m = 32; m; m >>= 1) s += __shfl_xor(s, m, 64);
    float nrm = sqrtf(s);
    float4 z;
    z.x = x.x / nrm; z.y = x.y / nrm; z.z = x.z / nrm; z.w = x.w / nrm;
    reinterpret_cast<float4*>(Z + (size_t)row * DIM)[lane] = z;
    float s2 = z.x*z.x + z.y*z.y + z.z*z.z + z.w*z.w;
    for (int m = 32; m; m >>= 1) s2 += __shfl_xor(s2, m, 64);
    if (lane == 0) nrm2[row] = s2;
}

__global__ void __launch_bounds__(256)
k_kernel(const float* __restrict__ Z, const float* __restrict__ nrm2,
         float* __restrict__ Km, __half* __restrict__ KP2) {
    const int i = blockIdx.x;
    const int j = blockIdx.y * 256 + threadIdx.x;
    __shared__ float zi[DIM];
    zi[threadIdx.x] = Z[(size_t)i * DIM + threadIdx.x];
    __syncthreads();
    const float4* zr = reinterpret_cast<const float4*>(Z + (size_t)j * DIM);
    float acc = 0.f;
    #pragma unroll 8
    for (int k = 0; k < DIM/4; ++k) {
        float4 v = zr[k];
        acc = fmaf(zi[4*k+0], v.x, acc);
        acc = fmaf(zi[4*k+1], v.y, acc);
        acc = fmaf(zi[4*k+2], v.z, acc);
        acc = fmaf(zi[4*k+3], v.w, acc);
    }
    float sq = nrm2[i] + nrm2[j] - 2.f * acc;
    sq = fmaxf(sq, 0.f);
    const float val = expf(-0.1f * sq);
    Km[(size_t)i * NZTOT + j] = val;
    // row-pair packed: KP2[(i/2)*768 + j*2 + (i&1)]
    if (j < BSZ) KP2[(size_t)(i >> 1) * 768 + j * 2 + (i & 1)] = __float2half(val);
}

// ---- phase-2 macros (named regs, compile-time indices) ----
#define KLDG(KA, KB, G) do {                                                  \
    KA = *reinterpret_cast<const uint4*>(kp2b + (size_t)(24*o + 2*(G))*1536 + 16*u);        \
    KB = *reinterpret_cast<const uint4*>(kp2b + (size_t)(24*o + 2*(G))*1536 + 1536 + 16*u); \
} while (0)

#define KRES(KA, KB, G) do {                                                  \
    KA = *reinterpret_cast<const uint4*>(kresb + ((o*4 + (G))*3072) + 16*u);          \
    KB = *reinterpret_cast<const uint4*>(kresb + ((o*4 + (G))*3072) + 1536 + 16*u);   \
} while (0)

#define GFMA(KA, KB, G) do {                                                  \
    const uint2 _z0 = *reinterpret_cast<const uint2*>(&zh[0][zb2 + 2*(G)]);   \
    const uint2 _z1 = *reinterpret_cast<const uint2*>(&zh[1][zb2 + 2*(G)]);   \
    const uint2 _z2 = *reinterpret_cast<const uint2*>(&zh[2][zb2 + 2*(G)]);   \
    const uint2 _z3 = *reinterpret_cast<const uint2*>(&zh[3][zb2 + 2*(G)]);   \
    acc0.x = dot2u((KA).x, _z0.x, acc0.x); acc0.x = dot2u((KB).x, _z0.y, acc0.x); \
    acc0.y = dot2u((KA).y, _z0.x, acc0.y); acc0.y = dot2u((KB).y, _z0.y, acc0.y); \
    acc0.z = dot2u((KA).z, _z0.x, acc0.z); acc0.z = dot2u((KB).z, _z0.y, acc0.z); \
    acc0.w = dot2u((KA).w, _z0.x, acc0.w); acc0.w = dot2u((KB).w, _z0.y, acc0.w); \
    acc1.x = dot2u((KA).x, _z1.x, acc1.x); acc1.x = dot2u((KB).x, _z1.y, acc1.x); \
    acc1.y = dot2u((KA).y, _z1.x, acc1.y); acc1.y = dot2u((KB).y, _z1.y, acc1.y); \
    acc1.z = dot2u((KA).z, _z1.x, acc1.z); acc1.z = dot2u((KB).z, _z1.y, acc1.z); \
    acc1.w = dot2u((KA).w, _z1.x, acc1.w); acc1.w = dot2u((KB).w, _z1.y, acc1.w); \
    acc2.x = dot2u((KA).x, _z2.x, acc2.x); acc2.x = dot2u((KB).x, _z2.y, acc2.x); \
    acc2.y = dot2u((KA).y, _z2.x, acc2.y); acc2.y = dot2u((KB).y, _z2.y, acc2.y); \
    acc2.z = dot2u((KA).z, _z2.x, acc2.z); acc2.z = dot2u((KB).z, _z2.y, acc2.z); \
    acc2.w = dot2u((KA).w, _z2.x, acc2.w); acc2.w = dot2u((KB).w, _z2.y, acc2.w); \
    acc3.x = dot2u((KA).x, _z3.x, acc3.x); acc3.x = dot2u((KB).x, _z3.y, acc3.x); \
    acc3.y = dot2u((KA).y, _z3.x, acc3.y); acc3.y = dot2u((KB).y, _z3.y, acc3.y); \
    acc3.z = dot2u((KA).z, _z3.x, acc3.z); acc3.z = dot2u((KB).z, _z3.y, acc3.z); \
    acc3.w = dot2u((KA).w, _z3.x, acc3.w); acc3.w = dot2u((KB).w, _z3.y, acc3.w); \
} while (0)

__global__ void __launch_bounds__(TPB, 1)
pgd_kernel(const float* __restrict__ Km, const __half* __restrict__ KP2,
           const float* __restrict__ alpha_init,
           float* __restrict__ afin, float* num, float* den, int* arr) {
    const int g    = blockIdx.x;     // 0..95
    const int c    = threadIdx.x;    // 0..767
    const int lane = c & 63;
    const int wv   = c >> 6;         // 0..11
    const int o    = c / 96;         // octant: rows [48o, 48o+48)
    const int u    = c - o * 96;     // owns cols 4u..4u+3
    const int zb2  = 24 * o;         // z half2-pair base for this octant

    extern __shared__ char dynlc[];
    char* const  kresb = dynlc;                       // 128 rows fp16 packed
    float* const wpart = (float*)(dynlc + KRESB);     // [8][RPB][384]

    __shared__ unsigned zh[RPB][200];   // z as packed half2 row-pairs (192 used)
    __shared__ float  rscr[12][10];     // per-wave: zn0..3, kbzn0..3, nump, an2
    __shared__ float  SD[8];            // S0..3, D0..3
    __shared__ unsigned long long scanm[2];

    const bool act = (c < BSZ);
    const char* const kp2b = (const char*)KP2;

    // ---- per-row init (diagonal thread c==b inert) ----
    float a[RPB], kb[RPB]; bool vld[RPB];
    #pragma unroll
    for (int r = 0; r < RPB; ++r) {
        const int b = g * RPB + r;
        vld[r] = act && (c != b);
        kb[r]  = act ? Km[(size_t)b * NZTOT + c] : 0.f;
        float v = 0.f;
        if (vld[r]) {
            const int i = c - (c > b ? 1 : 0);
            v = alpha_init[(size_t)b * BM1 + i];
            v = fminf(fmaxf(v, 0.f), 1.f);
        }
        a[r] = v;
    }
    float z[RPB];
    #pragma unroll
    for (int r = 0; r < RPB; ++r) z[r] = a[r];

    // ---- packed-fp16 register ring ----
    unsigned histx[RINGD], histy[RINGD];
    {
        const __half2 h01 = __floats2half2_rn(a[0], a[1]);
        const __half2 h23 = __floats2half2_rn(a[2], a[3]);
        const unsigned px = *reinterpret_cast<const unsigned*>(&h01);
        const unsigned py = *reinterpret_cast<const unsigned*>(&h23);
        #pragma unroll
        for (int s = 0; s < RINGD; ++s) { histx[s] = px; histy[s] = py; }
    }

    // ---- prologue: copy resident granules (0..3 of each octant) into LDS ----
    #pragma unroll
    for (int G = 0; G < 4; ++G) {
        const uint4 va = *reinterpret_cast<const uint4*>(kp2b + (size_t)(24*o + 2*G)*1536 + 16*u);
        const uint4 vb = *reinterpret_cast<const uint4*>(kp2b + (size_t)(24*o + 2*G)*1536 + 1536 + 16*u);
        *reinterpret_cast<uint4*>(kresb + (o*4 + G)*3072 + 16*u)        = va;
        *reinterpret_cast<uint4*>(kresb + (o*4 + G)*3072 + 1536 + 16*u) = vb;
    }

    // ---- prologue "phase 3" for t=0: z(0)=a, reductions ----
    {
        float an2 = 0.f;
        float vv[10];
        #pragma unroll
        for (int r = 0; r < RPB; ++r) {
            if (act) reinterpret_cast<__half*>(&zh[r][0])[c] = __float2half(z[r]);
            vv[r]     = z[r];
            vv[4 + r] = kb[r] * z[r];
            an2 += a[r] * a[r];
        }
        vv[8] = 0.f; vv[9] = an2;
        #pragma unroll
        for (int k = 0; k < 10; ++k) {
            float x = vv[k];
            x += __shfl_down(x, 32, 64); x += __shfl_down(x, 16, 64);
            x += __shfl_down(x,  8, 64); x += __shfl_down(x,  4, 64);
            x += __shfl_down(x,  2, 64); x += __shfl_down(x,  1, 64);
            if (lane == 0) rscr[wv][k] = x;
        }
        if (c < 2) scanm[c] = 0ULL;
    }
    __syncthreads();

    int stopT = -1;
    int sstate = 0, okv = 0, aval = 0;
    float nnv = 0.f, ddv = 1.f;

    for (int t = 0; t < NITER; ++t) {
        // ---- top: stop decision (from ballots of t-1) ----
        {
            const unsigned long long m0 = scanm[0], m1 = scanm[1];
            const int st = m0 ? (__ffsll(m0) - 1) : (m1 ? 63 + __ffsll(m1) : -1);
            if (st >= 0) { stopT = st; break; }
        }
        if (c < 8) {
            float s = 0.f;
            #pragma unroll
            for (int w = 0; w < 12; ++w) s += rscr[w][c];
            SD[c] = s;
        }
        // ---- fire-and-forget publish of iteration t-1 (c==0) ----
        if (c == 0) {
            float nb = 0.f, db = 0.f;
            #pragma unroll
            for (int w = 0; w < 12; ++w) { nb += rscr[w][8]; db += rscr[w][9]; }
            __hip_atomic_fetch_add(&den[t], db, __ATOMIC_RELAXED, __HIP_MEMORY_SCOPE_AGENT);
            if (t > 0) {
                __hip_atomic_fetch_add(&num[t - 1], nb, __ATOMIC_RELAXED, __HIP_MEMORY_SCOPE_AGENT);
                __hip_atomic_fetch_add(&arr[t - 1], 1, __ATOMIC_RELEASE, __HIP_MEMORY_SCOPE_AGENT);
            }
        }
        // ---- scan loads (state machine; evaluated in phase 3) ----
        if (c < NITER) {
            if (sstate == 0) {
                aval = __hip_atomic_load(&arr[c], __ATOMIC_RELAXED, __HIP_MEMORY_SCOPE_AGENT);
            } else if (sstate == 1) {
                nnv = __hip_atomic_load(&num[c], __ATOMIC_RELAXED, __HIP_MEMORY_SCOPE_AGENT);
                ddv = __hip_atomic_load(&den[c], __ATOMIC_RELAXED, __HIP_MEMORY_SCOPE_AGENT);
            }
        }

        // ---- phase 2: octant matvec: 4 LDS granules + 8 streamed (dot2) ----
        float4 acc0 = make_float4(0.f,0.f,0.f,0.f);
        float4 acc1 = make_float4(0.f,0.f,0.f,0.f);
        float4 acc2 = make_float4(0.f,0.f,0.f,0.f);
        float4 acc3 = make_float4(0.f,0.f,0.f,0.f);
        {
            uint4 kA0,kA1, kB0,kB1, kC0,kC1;
            KLDG(kA0,kA1, 4);
            KLDG(kB0,kB1, 5);
            { uint4 r0,r1; KRES(r0,r1, 0); GFMA(r0,r1, 0); }
            KLDG(kC0,kC1, 6);
            { uint4 r0,r1; KRES(r0,r1, 1); GFMA(r0,r1, 1); }
            { uint4 r0,r1; KRES(r0,r1, 2); GFMA(r0,r1, 2); }
            { uint4 r0,r1; KRES(r0,r1, 3); GFMA(r0,r1, 3); }
            GFMA(kA0,kA1, 4);  KLDG(kA0,kA1, 7);
            GFMA(kB0,kB1, 5);  KLDG(kB0,kB1, 8);
            GFMA(kC0,kC1, 6);  KLDG(kC0,kC1, 9);
            GFMA(kA0,kA1, 7);  KLDG(kA0,kA1, 10);
            GFMA(kB0,kB1, 8);  KLDG(kB0,kB1, 11);
            GFMA(kC0,kC1, 9);
            GFMA(kA0,kA1, 10);
            GFMA(kB0,kB1, 11);
        }
        *reinterpret_cast<float4*>(&wpart[(o * RPB + 0) * BSZ + 4*u]) = acc0;
        *reinterpret_cast<float4*>(&wpart[(o * RPB + 1) * BSZ + 4*u]) = acc1;
        *reinterpret_cast<float4*>(&wpart[(o * RPB + 2) * BSZ + 4*u]) = acc2;
        *reinterpret_cast<float4*>(&wpart[(o * RPB + 3) * BSZ + 4*u]) = acc3;
        __syncthreads();   // B2

        // ---- phase 3: step t, prepare t+1, reductions, scan eval ----
        float nump = 0.f, an2 = 0.f;
        float zn[RPB] = {0.f, 0.f, 0.f, 0.f};
        float anA[RPB] = {0.f, 0.f, 0.f, 0.f};
        if (act) {
            const float beta1 = (float)(t + 1) / ((float)(t + 1) + 3.0f);
            #pragma unroll
            for (int r = 0; r < RPB; ++r) {
                float w = 0.f;
                #pragma unroll
                for (int oo = 0; oo < 8; ++oo) w += wpart[(oo * RPB + r) * BSZ + c];
                float an = 0.f;
                if (vld[r]) {
                    const float grad = SD[r] * (1.f - kb[r]) + 0.1f * z[r] + w - SD[4 + r] - 2.0f;
                    an = z[r] - 0.001f * grad;
                    an = fminf(fmaxf(an, 0.f), 1.f);
                }
                const float d = an - a[r];
                nump += d * d;
                an2  += an * an;
                zn[r] = an + beta1 * (an - a[r]);
                anA[r] = an;
                a[r] = an;
            }
            #pragma unroll
            for (int r = 0; r < RPB; ++r) {
                reinterpret_cast<__half*>(&zh[r][0])[c] = __float2half(zn[r]);
                z[r] = zn[r];
            }
        }
        // ---- packed-fp16 register ring update ----
        {
            const int slot = t & (RINGD - 1);
            const __half2 h01 = __floats2half2_rn(anA[0], anA[1]);
            const __half2 h23 = __floats2half2_rn(anA[2], anA[3]);
            const unsigned px = *reinterpret_cast<const unsigned*>(&h01);
            const unsigned py = *reinterpret_cast<const unsigned*>(&h23);
            #pragma unroll
            for (int s2 = 0; s2 < RINGD; ++s2) {
                histx[s2] = (s2 == slot) ? px : histx[s2];
                histy[s2] = (s2 == slot) ? py : histy[s2];
            }
        }
        {
            float vv[10] = { zn[0], zn[1], zn[2], zn[3],
                             kb[0]*zn[0], kb[1]*zn[1], kb[2]*zn[2], kb[3]*zn[3],
                             nump, an2 };
            #pragma unroll
            for (int k = 0; k < 10; ++k) {
                float x = vv[k];
                x += __shfl_down(x, 32, 64); x += __shfl_down(x, 16, 64);
                x += __shfl_down(x,  8, 64); x += __shfl_down(x,  4, 64);
                x += __shfl_down(x,  2, 64); x += __shfl_down(x,  1, 64);
                if (lane == 0) rscr[wv][k] = x;
            }
        }
        // ---- scan state transitions + ballot ----
        if (c < NITER) {
            if (sstate == 0) { if (aval == ARRFULL) sstate = 1; }
            else if (sstate == 1) {
                okv = (sqrtf(nnv) / (sqrtf(ddv) + 1e-8f) < 0.01f) ? 1 : 0;
                sstate = 2;
            }
        }
        {
            const unsigned long long bm = __ballot(okv);
            if (lane == 0 && wv < 2) scanm[wv] = bm;
        }
        __syncthreads();   // B3
    }

    // ---- finalize ----
    float av[RPB];
    #pragma unroll
    for (int r = 0; r < RPB; ++r) av[r] = a[r];
    if (stopT >= 0) {
        unsigned sx = histx[0], sy = histy[0];
        const int sl = stopT & (RINGD - 1);
        #pragma unroll
        for (int s2 = 0; s2 < RINGD; ++s2) {
            sx = (s2 == sl) ? histx[s2] : sx;
            sy = (s2 == sl) ? histy[s2] : sy;
        }
        const float2 f01 = __half22float2(*reinterpret_cast<const __half2*>(&sx));
        const float2 f23 = __half22float2(*reinterpret_cast<const __half2*>(&sy));
        av[0] = f01.x; av[1] = f01.y; av[2] = f23.x; av[3] = f23.y;
    }
    if (act) {
        #pragma unroll
        for (int r = 0; r < RPB; ++r) {
            const int b = g * RPB + r;
            if (vld[r]) {
                const int i = c - (c > b ? 1 : 0);
                afin[(size_t)b * BM1 + i] = av[r];
            }
        }
    }
}

__global__ void __launch_bounds__(384)
loss_kernel(const float* __restrict__ Km, const float* __restrict__ afin,
            double* lossAcc) {
    const int b    = blockIdx.x;
    const int tid  = threadIdx.x;
    const int lane = tid & 63;
    const int wv   = tid >> 6;
    __shared__ double dscr[6][2];
    double np = 0.0, pp = 0.0;
    if (tid < BM1) {
        const float ay = afin[(size_t)b * BM1 + tid];
        const int   I  = tid + (tid >= b);
        np = (double)ay * (double)Km[(size_t)I * NZTOT + BSZ + b];
        pp = (double)ay * (double)Km[(size_t)b * NZTOT + BSZ + b];
    }
    for (int o = 32; o; o >>= 1) { np += __shfl_down(np, o, 64); pp += __shfl_down(pp, o, 64); }
    if (lane == 0) { dscr[wv][0] = np; dscr[wv][1] = pp; }
    __syncthreads();
    if (tid == 0) {
        double nb = 0.0, pb = 0.0;
        for (int w = 0; w < 6; ++w) { nb += dscr[w][0]; pb += dscr[w][1]; }
        __hip_atomic_fetch_add(&lossAcc[0], nb, __ATOMIC_RELAXED, __HIP_MEMORY_SCOPE_AGENT);
        __hip_atomic_fetch_add(&lossAcc[1], pb, __ATOMIC_RELAXED, __HIP_MEMORY_SCOPE_AGENT);
    }
}

__global__ void fin_kernel(const double* lossAcc, float* out) {
    out[0] = expf((float)(lossAcc[0] / 384.0 - lossAcc[1] / 384.0));
}

extern "C" void kernel_launch(void* const* d_in, const int* in_sizes, int n_in,
                              void* d_out, int out_size, void* d_ws, size_t ws_size,
                              hipStream_t stream) {
    const float* xis        = (const float*)d_in[0];
    const float* xjs        = (const float*)d_in[1];
    const float* alpha_init = (const float*)d_in[2];
    float* ws   = (float*)d_ws;
    float* Z    = ws + OFF_Z;
    float* nrm2 = ws + OFF_NRM;
    float* Km   = ws + OFF_K;
    __half* KP2 = (__half*)(ws + OFF_KH);
    float* afin = ws + OFF_A;
    float* num  = ws + OFF_NUM;
    float* den  = ws + OFF_DEN;
    int*   arr  = (int*)(ws + OFF_ARR);
    double* lossAcc = (double*)(ws + OFF_LOSS);
    float* out  = (float*)d_out;

    hipFuncSetAttribute((const void*)pgd_kernel,
                        hipFuncAttributeMaxDynamicSharedMemorySize, DYNB);

    hipLaunchKernelGGL(init_kernel, dim3(1), dim3(128), 0, stream, num, den, arr, lossAcc);
    hipLaunchKernelGGL(norm_kernel, dim3(NZTOT), dim3(64), 0, stream, xis, xjs, Z, nrm2);
    hipLaunchKernelGGL(k_kernel, dim3(BSZ, 3), dim3(256), 0, stream, Z, nrm2, Km, KP2);
    hipLaunchKernelGGL(pgd_kernel, dim3(NBLK), dim3(TPB), DYNB, stream,
                       Km, KP2, alpha_init, afin, num, den, arr);
    hipLaunchKernelGGL(loss_kernel, dim3(BSZ), dim3(384), 0, stream, Km, afin, lossAcc);
    hipLaunchKernelGGL(fin_kernel, dim3(1), dim3(1), 0, stream, lossAcc, out);
}

// Round 16
// 748.234 us; speedup vs baseline: 3.5304x; 1.1072x over previous
//
#include <hip/hip_runtime.h>
#include <hip/hip_fp16.h>
#include <math.h>

#define BSZ   384
#define BM1   383
#define DIM   256
#define NZTOT 768
#define NBLK  96
#define RPB   4
#define TPB   768
#define NITER 100
#define RINGD 8
#define ARRFULL NBLK
#define KRESB 98304                      // 128 rows fp16 packed in LDS (4 granules/octant)
#define WPARTB (8 * RPB * BSZ * 4)       // 49152
#define DYNB  (KRESB + WPARTB)           // 147456

// ---- ws layout (float offsets) ----
#define OFF_Z    0          // 768*256
#define OFF_NRM  196608     // 768
#define OFF_K    197376     // 384*768 fp32
#define OFF_KH   492288     // 384*384 fp16 row-pair packed (36864 floats)
#define OFF_A    639744     // 384*383 final alpha
#define OFF_NUM  786816     // NITER (pad 128)
#define OFF_DEN  786944
#define OFF_ARR  787072
#define OFF_LOSS 787200     // 2 doubles

__device__ __forceinline__ float2 h2f(unsigned int w) {
    return __half22float2(*reinterpret_cast<const __half2*>(&w));
}

__device__ __forceinline__ float dot2u(unsigned k, unsigned z, float acc) {
#if defined(__has_builtin) && __has_builtin(__builtin_amdgcn_fdot2)
    typedef _Float16 h2t __attribute__((ext_vector_type(2)));
    union { unsigned u; h2t h; } uk, uz;
    uk.u = k; uz.u = z;
    return __builtin_amdgcn_fdot2(uk.h, uz.h, acc, false);
#else
    const float2 fk = h2f(k); const float2 fz = h2f(z);
    return fmaf(fk.y, fz.y, fmaf(fk.x, fz.x, acc));
#endif
}

__global__ void init_kernel(float* num, float* den, int* arr, double* lossAcc) {
    int t = threadIdx.x;
    if (t < NITER) { num[t] = 0.f; den[t] = 0.f; arr[t] = 0; }
    if (t < 2) lossAcc[t] = 0.0;
}

__global__ void __launch_bounds__(64)
norm_kernel(const float* __restrict__ xis, const float* __restrict__ xjs,
            float* __restrict__ Z, float* __restrict__ nrm2) {
    const int row  = blockIdx.x;
    const int lane = threadIdx.x;
    const float* src = (row < BSZ) ? (xis + (size_t)row * DIM)
                                   : (xjs + (size_t)(row - BSZ) * DIM);
    float4 x = reinterpret_cast<const float4*>(src)[lane];
    float s = x.x*x.x + x.y*x.y + x.z*x.z + x.w*x.w;
    for (int m = 32; m; m >>= 1) s += __shfl_xor(s, m, 64);
    float nrm = sqrtf(s);
    float4 z;
    z.x = x.x / nrm; z.y = x.y / nrm; z.z = x.z / nrm; z.w = x.w / nrm;
    reinterpret_cast<float4*>(Z + (size_t)row * DIM)[lane] = z;
    float s2 = z.x*z.x + z.y*z.y + z.z*z.z + z.w*z.w;
    for (int m = 32; m; m >>= 1) s2 += __shfl_xor(s2, m, 64);
    if (lane == 0) nrm2[row] = s2;
}

__global__ void __launch_bounds__(256)
k_kernel(const float* __restrict__ Z, const float* __restrict__ nrm2,
         float* __restrict__ Km, __half* __restrict__ KP2) {
    const int i = blockIdx.x;
    const int j = blockIdx.y * 256 + threadIdx.x;
    __shared__ float zi[DIM];
    zi[threadIdx.x] = Z[(size_t)i * DIM + threadIdx.x];
    __syncthreads();
    const float4* zr = reinterpret_cast<const float4*>(Z + (size_t)j * DIM);
    float acc = 0.f;
    #pragma unroll 8
    for (int k = 0; k < DIM/4; ++k) {
        float4 v = zr[k];
        acc = fmaf(zi[4*k+0], v.x, acc);
        acc = fmaf(zi[4*k+1], v.y, acc);
        acc = fmaf(zi[4*k+2], v.z, acc);
        acc = fmaf(zi[4*k+3], v.w, acc);
    }
    float sq = nrm2[i] + nrm2[j] - 2.f * acc;
    sq = fmaxf(sq, 0.f);
    const float val = expf(-0.1f * sq);
    Km[(size_t)i * NZTOT + j] = val;
    // row-pair packed: KP2[(i/2)*768 + j*2 + (i&1)]
    if (j < BSZ) KP2[(size_t)(i >> 1) * 768 + j * 2 + (i & 1)] = __float2half(val);
}

// ---- phase-2 macros (named regs, compile-time indices) ----
#define KLDG(KA, KB, G) do {                                                  \
    KA = *reinterpret_cast<const uint4*>(kp2b + (size_t)(24*o + 2*(G))*1536 + 16*u);        \
    KB = *reinterpret_cast<const uint4*>(kp2b + (size_t)(24*o + 2*(G))*1536 + 1536 + 16*u); \
} while (0)

#define KRES(KA, KB, G) do {                                                  \
    KA = *reinterpret_cast<const uint4*>(kresb + ((o*4 + (G))*3072) + 16*u);          \
    KB = *reinterpret_cast<const uint4*>(kresb + ((o*4 + (G))*3072) + 1536 + 16*u);   \
} while (0)

#define GFMA(KA, KB, G) do {                                                  \
    const uint2 _z0 = *reinterpret_cast<const uint2*>(&zh[0][zb2 + 2*(G)]);   \
    const uint2 _z1 = *reinterpret_cast<const uint2*>(&zh[1][zb2 + 2*(G)]);   \
    const uint2 _z2 = *reinterpret_cast<const uint2*>(&zh[2][zb2 + 2*(G)]);   \
    const uint2 _z3 = *reinterpret_cast<const uint2*>(&zh[3][zb2 + 2*(G)]);   \
    acc0.x = dot2u((KA).x, _z0.x, acc0.x); acc0.x = dot2u((KB).x, _z0.y, acc0.x); \
    acc0.y = dot2u((KA).y, _z0.x, acc0.y); acc0.y = dot2u((KB).y, _z0.y, acc0.y); \
    acc0.z = dot2u((KA).z, _z0.x, acc0.z); acc0.z = dot2u((KB).z, _z0.y, acc0.z); \
    acc0.w = dot2u((KA).w, _z0.x, acc0.w); acc0.w = dot2u((KB).w, _z0.y, acc0.w); \
    acc1.x = dot2u((KA).x, _z1.x, acc1.x); acc1.x = dot2u((KB).x, _z1.y, acc1.x); \
    acc1.y = dot2u((KA).y, _z1.x, acc1.y); acc1.y = dot2u((KB).y, _z1.y, acc1.y); \
    acc1.z = dot2u((KA).z, _z1.x, acc1.z); acc1.z = dot2u((KB).z, _z1.y, acc1.z); \
    acc1.w = dot2u((KA).w, _z1.x, acc1.w); acc1.w = dot2u((KB).w, _z1.y, acc1.w); \
    acc2.x = dot2u((KA).x, _z2.x, acc2.x); acc2.x = dot2u((KB).x, _z2.y, acc2.x); \
    acc2.y = dot2u((KA).y, _z2.x, acc2.y); acc2.y = dot2u((KB).y, _z2.y, acc2.y); \
    acc2.z = dot2u((KA).z, _z2.x, acc2.z); acc2.z = dot2u((KB).z, _z2.y, acc2.z); \
    acc2.w = dot2u((KA).w, _z2.x, acc2.w); acc2.w = dot2u((KB).w, _z2.y, acc2.w); \
    acc3.x = dot2u((KA).x, _z3.x, acc3.x); acc3.x = dot2u((KB).x, _z3.y, acc3.x); \
    acc3.y = dot2u((KA).y, _z3.x, acc3.y); acc3.y = dot2u((KB).y, _z3.y, acc3.y); \
    acc3.z = dot2u((KA).z, _z3.x, acc3.z); acc3.z = dot2u((KB).z, _z3.y, acc3.z); \
    acc3.w = dot2u((KA).w, _z3.x, acc3.w); acc3.w = dot2u((KB).w, _z3.y, acc3.w); \
} while (0)

__global__ void __launch_bounds__(TPB, 1)
pgd_kernel(const float* __restrict__ Km, const __half* __restrict__ KP2,
           const float* __restrict__ alpha_init,
           float* __restrict__ afin, float* num, float* den, int* arr) {
    const int g    = blockIdx.x;     // 0..95
    const int c    = threadIdx.x;    // 0..767
    const int lane = c & 63;
    const int wv   = c >> 6;         // 0..11
    const int o    = c / 96;         // octant: rows [48o, 48o+48)
    const int u    = c - o * 96;     // owns cols 4u..4u+3
    const int zb2  = 24 * o;         // z half2-pair base for this octant

    extern __shared__ char dynlc[];
    char* const  kresb = dynlc;                       // 128 rows fp16 packed
    float* const wpart = (float*)(dynlc + KRESB);     // [8][RPB][384]

    __shared__ unsigned zh[RPB][200];   // z as packed half2 row-pairs (192 used)
    __shared__ float  rscr[12][10];     // per-wave: zn0..3, kbzn0..3, nump, an2
    __shared__ float  SD[8];            // S0..3, D0..3
    __shared__ unsigned long long scanm[2];

    const bool act = (c < BSZ);
    const char* const kp2b = (const char*)KP2;

    // ---- per-row init (diagonal thread c==b inert) ----
    float a[RPB], kb[RPB]; bool vld[RPB];
    #pragma unroll
    for (int r = 0; r < RPB; ++r) {
        const int b = g * RPB + r;
        vld[r] = act && (c != b);
        kb[r]  = act ? Km[(size_t)b * NZTOT + c] : 0.f;
        float v = 0.f;
        if (vld[r]) {
            const int i = c - (c > b ? 1 : 0);
            v = alpha_init[(size_t)b * BM1 + i];
            v = fminf(fmaxf(v, 0.f), 1.f);
        }
        a[r] = v;
    }
    float z[RPB];
    #pragma unroll
    for (int r = 0; r < RPB; ++r) z[r] = a[r];

    // ---- packed-fp16 register ring ----
    unsigned histx[RINGD], histy[RINGD];
    {
        const __half2 h01 = __floats2half2_rn(a[0], a[1]);
        const __half2 h23 = __floats2half2_rn(a[2], a[3]);
        const unsigned px = *reinterpret_cast<const unsigned*>(&h01);
        const unsigned py = *reinterpret_cast<const unsigned*>(&h23);
        #pragma unroll
        for (int s = 0; s < RINGD; ++s) { histx[s] = px; histy[s] = py; }
    }

    // ---- prologue: granules 0..3 -> LDS; granules 4..7 -> persistent registers ----
    #pragma unroll
    for (int G = 0; G < 4; ++G) {
        const uint4 va = *reinterpret_cast<const uint4*>(kp2b + (size_t)(24*o + 2*G)*1536 + 16*u);
        const uint4 vb = *reinterpret_cast<const uint4*>(kp2b + (size_t)(24*o + 2*G)*1536 + 1536 + 16*u);
        *reinterpret_cast<uint4*>(kresb + (o*4 + G)*3072 + 16*u)        = va;
        *reinterpret_cast<uint4*>(kresb + (o*4 + G)*3072 + 1536 + 16*u) = vb;
    }
    uint4 p40,p41, p50,p51, p60,p61, p70,p71;
    KLDG(p40,p41, 4);
    KLDG(p50,p51, 5);
    KLDG(p60,p61, 6);
    KLDG(p70,p71, 7);

    // ---- prologue "phase 3" for t=0: z(0)=a, reductions ----
    {
        float an2 = 0.f;
        float vv[10];
        #pragma unroll
        for (int r = 0; r < RPB; ++r) {
            if (act) reinterpret_cast<__half*>(&zh[r][0])[c] = __float2half(z[r]);
            vv[r]     = z[r];
            vv[4 + r] = kb[r] * z[r];
            an2 += a[r] * a[r];
        }
        vv[8] = 0.f; vv[9] = an2;
        #pragma unroll
        for (int k = 0; k < 10; ++k) {
            float x = vv[k];
            x += __shfl_down(x, 32, 64); x += __shfl_down(x, 16, 64);
            x += __shfl_down(x,  8, 64); x += __shfl_down(x,  4, 64);
            x += __shfl_down(x,  2, 64); x += __shfl_down(x,  1, 64);
            if (lane == 0) rscr[wv][k] = x;
        }
        if (c < 2) scanm[c] = 0ULL;
    }
    __syncthreads();

    int stopT = -1;
    int sstate = 0, okv = 0, aval = 0;
    float nnv = 0.f, ddv = 1.f;

    for (int t = 0; t < NITER; ++t) {
        // ---- top: stop decision (from ballots of t-1) ----
        {
            const unsigned long long m0 = scanm[0], m1 = scanm[1];
            const int st = m0 ? (__ffsll(m0) - 1) : (m1 ? 63 + __ffsll(m1) : -1);
            if (st >= 0) { stopT = st; break; }
        }
        if (c < 8) {
            float s = 0.f;
            #pragma unroll
            for (int w = 0; w < 12; ++w) s += rscr[w][c];
            SD[c] = s;
        }
        // ---- fire-and-forget publish of iteration t-1 (c==0) ----
        if (c == 0) {
            float nb = 0.f, db = 0.f;
            #pragma unroll
            for (int w = 0; w < 12; ++w) { nb += rscr[w][8]; db += rscr[w][9]; }
            __hip_atomic_fetch_add(&den[t], db, __ATOMIC_RELAXED, __HIP_MEMORY_SCOPE_AGENT);
            if (t > 0) {
                __hip_atomic_fetch_add(&num[t - 1], nb, __ATOMIC_RELAXED, __HIP_MEMORY_SCOPE_AGENT);
                __hip_atomic_fetch_add(&arr[t - 1], 1, __ATOMIC_RELEASE, __HIP_MEMORY_SCOPE_AGENT);
            }
        }
        // ---- scan loads (state machine; evaluated in phase 3) ----
        if (c < NITER) {
            if (sstate == 0) {
                aval = __hip_atomic_load(&arr[c], __ATOMIC_RELAXED, __HIP_MEMORY_SCOPE_AGENT);
            } else if (sstate == 1) {
                nnv = __hip_atomic_load(&num[c], __ATOMIC_RELAXED, __HIP_MEMORY_SCOPE_AGENT);
                ddv = __hip_atomic_load(&den[c], __ATOMIC_RELAXED, __HIP_MEMORY_SCOPE_AGENT);
            }
        }

        // ---- phase 2: 4 LDS granules + 4 register granules + 4 streamed ----
        float4 acc0 = make_float4(0.f,0.f,0.f,0.f);
        float4 acc1 = make_float4(0.f,0.f,0.f,0.f);
        float4 acc2 = make_float4(0.f,0.f,0.f,0.f);
        float4 acc3 = make_float4(0.f,0.f,0.f,0.f);
        {
            uint4 kA0,kA1, kB0,kB1;
            KLDG(kA0,kA1, 8);
            KLDG(kB0,kB1, 9);
            { uint4 r0,r1; KRES(r0,r1, 0); GFMA(r0,r1, 0); }
            { uint4 r0,r1; KRES(r0,r1, 1); GFMA(r0,r1, 1); }
            { uint4 r0,r1; KRES(r0,r1, 2); GFMA(r0,r1, 2); }
            { uint4 r0,r1; KRES(r0,r1, 3); GFMA(r0,r1, 3); }
            GFMA(p40,p41, 4);
            GFMA(p50,p51, 5);
            GFMA(kA0,kA1, 8);  KLDG(kA0,kA1, 10);
            GFMA(p60,p61, 6);
            GFMA(kB0,kB1, 9);  KLDG(kB0,kB1, 11);
            GFMA(p70,p71, 7);
            GFMA(kA0,kA1, 10);
            GFMA(kB0,kB1, 11);
        }
        *reinterpret_cast<float4*>(&wpart[(o * RPB + 0) * BSZ + 4*u]) = acc0;
        *reinterpret_cast<float4*>(&wpart[(o * RPB + 1) * BSZ + 4*u]) = acc1;
        *reinterpret_cast<float4*>(&wpart[(o * RPB + 2) * BSZ + 4*u]) = acc2;
        *reinterpret_cast<float4*>(&wpart[(o * RPB + 3) * BSZ + 4*u]) = acc3;
        __syncthreads();   // B2

        // ---- phase 3: step t, prepare t+1, reductions, scan eval ----
        float nump = 0.f, an2 = 0.f;
        float zn[RPB] = {0.f, 0.f, 0.f, 0.f};
        float anA[RPB] = {0.f, 0.f, 0.f, 0.f};
        if (act) {
            const float beta1 = (float)(t + 1) / ((float)(t + 1) + 3.0f);
            #pragma unroll
            for (int r = 0; r < RPB; ++r) {
                float w = 0.f;
                #pragma unroll
                for (int oo = 0; oo < 8; ++oo) w += wpart[(oo * RPB + r) * BSZ + c];
                float an = 0.f;
                if (vld[r]) {
                    const float grad = SD[r] * (1.f - kb[r]) + 0.1f * z[r] + w - SD[4 + r] - 2.0f;
                    an = z[r] - 0.001f * grad;
                    an = fminf(fmaxf(an, 0.f), 1.f);
                }
                const float d = an - a[r];
                nump += d * d;
                an2  += an * an;
                zn[r] = an + beta1 * (an - a[r]);
                anA[r] = an;
                a[r] = an;
            }
            #pragma unroll
            for (int r = 0; r < RPB; ++r) {
                reinterpret_cast<__half*>(&zh[r][0])[c] = __float2half(zn[r]);
                z[r] = zn[r];
            }
        }
        // ---- packed-fp16 register ring update ----
        {
            const int slot = t & (RINGD - 1);
            const __half2 h01 = __floats2half2_rn(anA[0], anA[1]);
            const __half2 h23 = __floats2half2_rn(anA[2], anA[3]);
            const unsigned px = *reinterpret_cast<const unsigned*>(&h01);
            const unsigned py = *reinterpret_cast<const unsigned*>(&h23);
            #pragma unroll
            for (int s2 = 0; s2 < RINGD; ++s2) {
                histx[s2] = (s2 == slot) ? px : histx[s2];
                histy[s2] = (s2 == slot) ? py : histy[s2];
            }
        }
        {
            float vv[10] = { zn[0], zn[1], zn[2], zn[3],
                             kb[0]*zn[0], kb[1]*zn[1], kb[2]*zn[2], kb[3]*zn[3],
                             nump, an2 };
            #pragma unroll
            for (int k = 0; k < 10; ++k) {
                float x = vv[k];
                x += __shfl_down(x, 32, 64); x += __shfl_down(x, 16, 64);
                x += __shfl_down(x,  8, 64); x += __shfl_down(x,  4, 64);
                x += __shfl_down(x,  2, 64); x += __shfl_down(x,  1, 64);
                if (lane == 0) rscr[wv][k] = x;
            }
        }
        // ---- scan state transitions + ballot ----
        if (c < NITER) {
            if (sstate == 0) { if (aval == ARRFULL) sstate = 1; }
            else if (sstate == 1) {
                okv = (sqrtf(nnv) / (sqrtf(ddv) + 1e-8f) < 0.01f) ? 1 : 0;
                sstate = 2;
            }
        }
        {
            const unsigned long long bm = __ballot(okv);
            if (lane == 0 && wv < 2) scanm[wv] = bm;
        }
        __syncthreads();   // B3
    }

    // ---- finalize ----
    float av[RPB];
    #pragma unroll
    for (int r = 0; r < RPB; ++r) av[r] = a[r];
    if (stopT >= 0) {
        unsigned sx = histx[0], sy = histy[0];
        const int sl = stopT & (RINGD - 1);
        #pragma unroll
        for (int s2 = 0; s2 < RINGD; ++s2) {
            sx = (s2 == sl) ? histx[s2] : sx;
            sy = (s2 == sl) ? histy[s2] : sy;
        }
        const float2 f01 = __half22float2(*reinterpret_cast<const __half2*>(&sx));
        const float2 f23 = __half22float2(*reinterpret_cast<const __half2*>(&sy));
        av[0] = f01.x; av[1] = f01.y; av[2] = f23.x; av[3] = f23.y;
    }
    if (act) {
        #pragma unroll
        for (int r = 0; r < RPB; ++r) {
            const int b = g * RPB + r;
            if (vld[r]) {
                const int i = c - (c > b ? 1 : 0);
                afin[(size_t)b * BM1 + i] = av[r];
            }
        }
    }
}

__global__ void __launch_bounds__(384)
loss_kernel(const float* __restrict__ Km, const float* __restrict__ afin,
            double* lossAcc) {
    const int b    = blockIdx.x;
    const int tid  = threadIdx.x;
    const int lane = tid & 63;
    const int wv   = tid >> 6;
    __shared__ double dscr[6][2];
    double np = 0.0, pp = 0.0;
    if (tid < BM1) {
        const float ay = afin[(size_t)b * BM1 + tid];
        const int   I  = tid + (tid >= b);
        np = (double)ay * (double)Km[(size_t)I * NZTOT + BSZ + b];
        pp = (double)ay * (double)Km[(size_t)b * NZTOT + BSZ + b];
    }
    for (int o = 32; o; o >>= 1) { np += __shfl_down(np, o, 64); pp += __shfl_down(pp, o, 64); }
    if (lane == 0) { dscr[wv][0] = np; dscr[wv][1] = pp; }
    __syncthreads();
    if (tid == 0) {
        double nb = 0.0, pb = 0.0;
        for (int w = 0; w < 6; ++w) { nb += dscr[w][0]; pb += dscr[w][1]; }
        __hip_atomic_fetch_add(&lossAcc[0], nb, __ATOMIC_RELAXED, __HIP_MEMORY_SCOPE_AGENT);
        __hip_atomic_fetch_add(&lossAcc[1], pb, __ATOMIC_RELAXED, __HIP_MEMORY_SCOPE_AGENT);
    }
}

__global__ void fin_kernel(const double* lossAcc, float* out) {
    out[0] = expf((float)(lossAcc[0] / 384.0 - lossAcc[1] / 384.0));
}

extern "C" void kernel_launch(void* const* d_in, const int* in_sizes, int n_in,
                              void* d_out, int out_size, void* d_ws, size_t ws_size,
                              hipStream_t stream) {
    const float* xis        = (const float*)d_in[0];
    const float* xjs        = (const float*)d_in[1];
    const float* alpha_init = (const float*)d_in[2];
    float* ws   = (float*)d_ws;
    float* Z    = ws + OFF_Z;
    float* nrm2 = ws + OFF_NRM;
    float* Km   = ws + OFF_K;
    __half* KP2 = (__half*)(ws + OFF_KH);
    float* afin = ws + OFF_A;
    float* num  = ws + OFF_NUM;
    float* den  = ws + OFF_DEN;
    int*   arr  = (int*)(ws + OFF_ARR);
    double* lossAcc = (double*)(ws + OFF_LOSS);
    float* out  = (float*)d_out;

    hipFuncSetAttribute((const void*)pgd_kernel,
                        hipFuncAttributeMaxDynamicSharedMemorySize, DYNB);

    hipLaunchKernelGGL(init_kernel, dim3(1), dim3(128), 0, stream, num, den, arr, lossAcc);
    hipLaunchKernelGGL(norm_kernel, dim3(NZTOT), dim3(64), 0, stream, xis, xjs, Z, nrm2);
    hipLaunchKernelGGL(k_kernel, dim3(BSZ, 3), dim3(256), 0, stream, Z, nrm2, Km, KP2);
    hipLaunchKernelGGL(pgd_kernel, dim3(NBLK), dim3(TPB), DYNB, stream,
                       Km, KP2, alpha_init, afin, num, den, arr);
    hipLaunchKernelGGL(loss_kernel, dim3(BSZ), dim3(384), 0, stream, Km, afin, lossAcc);
    hipLaunchKernelGGL(fin_kernel, dim3(1), dim3(1), 0, stream, lossAcc, out);
}

// Round 17
// 740.223 us; speedup vs baseline: 3.5686x; 1.0108x over previous
//
#include <hip/hip_runtime.h>
#include <hip/hip_fp16.h>
#include <math.h>

#define BSZ   384
#define BM1   383
#define DIM   256
#define NZTOT 768
#define NBLK  96
#define RPB   4
#define TPB   768
#define NITER 100
#define RINGD 8
#define ARRFULL NBLK
#define KRESB 98304                      // 128 rows fp16 packed in LDS (4 granules/octant)
#define WPARTB (8 * RPB * BSZ * 4)       // 49152
#define DYNB  (KRESB + WPARTB)           // 147456

// ---- ws layout (float offsets) ----
#define OFF_Z    0          // 768*256
#define OFF_NRM  196608     // 768
#define OFF_K    197376     // 384*768 fp32
#define OFF_KH   492288     // 384*384 fp16 row-pair packed (36864 floats)
#define OFF_A    639744     // 384*383 final alpha
#define OFF_NUM  786816     // NITER (pad 128)
#define OFF_DEN  786944
#define OFF_ARR  787072
#define OFF_LOSS 787200     // 2 doubles

__device__ __forceinline__ float2 h2f(unsigned int w) {
    return __half22float2(*reinterpret_cast<const __half2*>(&w));
}

__device__ __forceinline__ float dot2u(unsigned k, unsigned z, float acc) {
#if defined(__has_builtin) && __has_builtin(__builtin_amdgcn_fdot2)
    typedef _Float16 h2t __attribute__((ext_vector_type(2)));
    union { unsigned u; h2t h; } uk, uz;
    uk.u = k; uz.u = z;
    return __builtin_amdgcn_fdot2(uk.h, uz.h, acc, false);
#else
    const float2 fk = h2f(k); const float2 fz = h2f(z);
    return fmaf(fk.y, fz.y, fmaf(fk.x, fz.x, acc));
#endif
}

__global__ void init_kernel(float* num, float* den, int* arr, double* lossAcc) {
    int t = threadIdx.x;
    if (t < NITER) { num[t] = 0.f; den[t] = 0.f; arr[t] = 0; }
    if (t < 2) lossAcc[t] = 0.0;
}

__global__ void __launch_bounds__(64)
norm_kernel(const float* __restrict__ xis, const float* __restrict__ xjs,
            float* __restrict__ Z, float* __restrict__ nrm2) {
    const int row  = blockIdx.x;
    const int lane = threadIdx.x;
    const float* src = (row < BSZ) ? (xis + (size_t)row * DIM)
                                   : (xjs + (size_t)(row - BSZ) * DIM);
    float4 x = reinterpret_cast<const float4*>(src)[lane];
    float s = x.x*x.x + x.y*x.y + x.z*x.z + x.w*x.w;
    for (int m = 32; m; m >>= 1) s += __shfl_xor(s, m, 64);
    float nrm = sqrtf(s);
    float4 z;
    z.x = x.x / nrm; z.y = x.y / nrm; z.z = x.z / nrm; z.w = x.w / nrm;
    reinterpret_cast<float4*>(Z + (size_t)row * DIM)[lane] = z;
    float s2 = z.x*z.x + z.y*z.y + z.z*z.z + z.w*z.w;
    for (int m = 32; m; m >>= 1) s2 += __shfl_xor(s2, m, 64);
    if (lane == 0) nrm2[row] = s2;
}

__global__ void __launch_bounds__(256)
k_kernel(const float* __restrict__ Z, const float* __restrict__ nrm2,
         float* __restrict__ Km, __half* __restrict__ KP2) {
    const int i = blockIdx.x;
    const int j = blockIdx.y * 256 + threadIdx.x;
    __shared__ float zi[DIM];
    zi[threadIdx.x] = Z[(size_t)i * DIM + threadIdx.x];
    __syncthreads();
    const float4* zr = reinterpret_cast<const float4*>(Z + (size_t)j * DIM);
    float acc = 0.f;
    #pragma unroll 8
    for (int k = 0; k < DIM/4; ++k) {
        float4 v = zr[k];
        acc = fmaf(zi[4*k+0], v.x, acc);
        acc = fmaf(zi[4*k+1], v.y, acc);
        acc = fmaf(zi[4*k+2], v.z, acc);
        acc = fmaf(zi[4*k+3], v.w, acc);
    }
    float sq = nrm2[i] + nrm2[j] - 2.f * acc;
    sq = fmaxf(sq, 0.f);
    const float val = expf(-0.1f * sq);
    Km[(size_t)i * NZTOT + j] = val;
    // row-pair packed: KP2[(i/2)*768 + j*2 + (i&1)]
    if (j < BSZ) KP2[(size_t)(i >> 1) * 768 + j * 2 + (i & 1)] = __float2half(val);
}

// ---- phase-2 macros (named regs, compile-time indices) ----
#define KLDG(KA, KB, G) do {                                                  \
    KA = *reinterpret_cast<const uint4*>(kp2b + (size_t)(24*o + 2*(G))*1536 + 16*u);        \
    KB = *reinterpret_cast<const uint4*>(kp2b + (size_t)(24*o + 2*(G))*1536 + 1536 + 16*u); \
} while (0)

#define KRES(KA, KB, G) do {                                                  \
    KA = *reinterpret_cast<const uint4*>(kresb + ((o*4 + (G))*3072) + 16*u);          \
    KB = *reinterpret_cast<const uint4*>(kresb + ((o*4 + (G))*3072) + 1536 + 16*u);   \
} while (0)

#define GFMA(KA, KB, G) do {                                                  \
    const uint2 _z0 = *reinterpret_cast<const uint2*>(&zh[0][zb2 + 2*(G)]);   \
    const uint2 _z1 = *reinterpret_cast<const uint2*>(&zh[1][zb2 + 2*(G)]);   \
    const uint2 _z2 = *reinterpret_cast<const uint2*>(&zh[2][zb2 + 2*(G)]);   \
    const uint2 _z3 = *reinterpret_cast<const uint2*>(&zh[3][zb2 + 2*(G)]);   \
    acc0.x = dot2u((KA).x, _z0.x, acc0.x); acc0.x = dot2u((KB).x, _z0.y, acc0.x); \
    acc0.y = dot2u((KA).y, _z0.x, acc0.y); acc0.y = dot2u((KB).y, _z0.y, acc0.y); \
    acc0.z = dot2u((KA).z, _z0.x, acc0.z); acc0.z = dot2u((KB).z, _z0.y, acc0.z); \
    acc0.w = dot2u((KA).w, _z0.x, acc0.w); acc0.w = dot2u((KB).w, _z0.y, acc0.w); \
    acc1.x = dot2u((KA).x, _z1.x, acc1.x); acc1.x = dot2u((KB).x, _z1.y, acc1.x); \
    acc1.y = dot2u((KA).y, _z1.x, acc1.y); acc1.y = dot2u((KB).y, _z1.y, acc1.y); \
    acc1.z = dot2u((KA).z, _z1.x, acc1.z); acc1.z = dot2u((KB).z, _z1.y, acc1.z); \
    acc1.w = dot2u((KA).w, _z1.x, acc1.w); acc1.w = dot2u((KB).w, _z1.y, acc1.w); \
    acc2.x = dot2u((KA).x, _z2.x, acc2.x); acc2.x = dot2u((KB).x, _z2.y, acc2.x); \
    acc2.y = dot2u((KA).y, _z2.x, acc2.y); acc2.y = dot2u((KB).y, _z2.y, acc2.y); \
    acc2.z = dot2u((KA).z, _z2.x, acc2.z); acc2.z = dot2u((KB).z, _z2.y, acc2.z); \
    acc2.w = dot2u((KA).w, _z2.x, acc2.w); acc2.w = dot2u((KB).w, _z2.y, acc2.w); \
    acc3.x = dot2u((KA).x, _z3.x, acc3.x); acc3.x = dot2u((KB).x, _z3.y, acc3.x); \
    acc3.y = dot2u((KA).y, _z3.x, acc3.y); acc3.y = dot2u((KB).y, _z3.y, acc3.y); \
    acc3.z = dot2u((KA).z, _z3.x, acc3.z); acc3.z = dot2u((KB).z, _z3.y, acc3.z); \
    acc3.w = dot2u((KA).w, _z3.x, acc3.w); acc3.w = dot2u((KB).w, _z3.y, acc3.w); \
} while (0)

__global__ void __launch_bounds__(TPB, 1)
pgd_kernel(const float* __restrict__ Km, const __half* __restrict__ KP2,
           const float* __restrict__ alpha_init,
           float* __restrict__ afin, float* num, float* den, int* arr) {
    const int g    = blockIdx.x;     // 0..95
    const int c    = threadIdx.x;    // 0..767
    const int lane = c & 63;
    const int wv   = c >> 6;         // 0..11
    const int o    = c / 96;         // octant: rows [48o, 48o+48)
    const int u    = c - o * 96;     // owns cols 4u..4u+3
    const int zb2  = 24 * o;         // z half2-pair base for this octant

    extern __shared__ char dynlc[];
    char* const  kresb = dynlc;                       // 128 rows fp16 packed
    float* const wpart = (float*)(dynlc + KRESB);     // [8][RPB][384]

    __shared__ unsigned zh[RPB][200];   // z as packed half2 row-pairs (192 used)
    __shared__ float  rscr[12][10];     // per-wave: zn0..3, kbzn0..3, nump, an2
    __shared__ float  SD[8];            // S0..3, D0..3
    __shared__ unsigned long long scanm[2];

    const bool act = (c < BSZ);
    const char* const kp2b = (const char*)KP2;

    // ---- per-row init (diagonal thread c==b inert) ----
    float a[RPB], kb[RPB]; bool vld[RPB];
    #pragma unroll
    for (int r = 0; r < RPB; ++r) {
        const int b = g * RPB + r;
        vld[r] = act && (c != b);
        kb[r]  = act ? Km[(size_t)b * NZTOT + c] : 0.f;
        float v = 0.f;
        if (vld[r]) {
            const int i = c - (c > b ? 1 : 0);
            v = alpha_init[(size_t)b * BM1 + i];
            v = fminf(fmaxf(v, 0.f), 1.f);
        }
        a[r] = v;
    }
    float z[RPB];
    #pragma unroll
    for (int r = 0; r < RPB; ++r) z[r] = a[r];

    // ---- packed-fp16 register ring ----
    unsigned histx[RINGD], histy[RINGD];
    {
        const __half2 h01 = __floats2half2_rn(a[0], a[1]);
        const __half2 h23 = __floats2half2_rn(a[2], a[3]);
        const unsigned px = *reinterpret_cast<const unsigned*>(&h01);
        const unsigned py = *reinterpret_cast<const unsigned*>(&h23);
        #pragma unroll
        for (int s = 0; s < RINGD; ++s) { histx[s] = px; histy[s] = py; }
    }

    // ---- prologue: granules 0..3 -> LDS; granules 4..11 -> persistent registers ----
    #pragma unroll
    for (int G = 0; G < 4; ++G) {
        const uint4 va = *reinterpret_cast<const uint4*>(kp2b + (size_t)(24*o + 2*G)*1536 + 16*u);
        const uint4 vb = *reinterpret_cast<const uint4*>(kp2b + (size_t)(24*o + 2*G)*1536 + 1536 + 16*u);
        *reinterpret_cast<uint4*>(kresb + (o*4 + G)*3072 + 16*u)        = va;
        *reinterpret_cast<uint4*>(kresb + (o*4 + G)*3072 + 1536 + 16*u) = vb;
    }
    uint4 p40,p41, p50,p51, p60,p61, p70,p71;
    uint4 p80,p81, p90,p91, pA0,pA1, pB0,pB1;
    KLDG(p40,p41, 4);
    KLDG(p50,p51, 5);
    KLDG(p60,p61, 6);
    KLDG(p70,p71, 7);
    KLDG(p80,p81, 8);
    KLDG(p90,p91, 9);
    KLDG(pA0,pA1, 10);
    KLDG(pB0,pB1, 11);

    // ---- prologue "phase 3" for t=0: z(0)=a, reductions ----
    {
        float an2 = 0.f;
        float vv[10];
        #pragma unroll
        for (int r = 0; r < RPB; ++r) {
            if (act) reinterpret_cast<__half*>(&zh[r][0])[c] = __float2half(z[r]);
            vv[r]     = z[r];
            vv[4 + r] = kb[r] * z[r];
            an2 += a[r] * a[r];
        }
        vv[8] = 0.f; vv[9] = an2;
        #pragma unroll
        for (int k = 0; k < 10; ++k) {
            float x = vv[k];
            x += __shfl_down(x, 32, 64); x += __shfl_down(x, 16, 64);
            x += __shfl_down(x,  8, 64); x += __shfl_down(x,  4, 64);
            x += __shfl_down(x,  2, 64); x += __shfl_down(x,  1, 64);
            if (lane == 0) rscr[wv][k] = x;
        }
        if (c < 2) scanm[c] = 0ULL;
    }
    __syncthreads();

    int stopT = -1;
    int sstate = 0, okv = 0, aval = 0;
    float nnv = 0.f, ddv = 1.f;

    for (int t = 0; t < NITER; ++t) {
        // ---- top: stop decision (from ballots of t-1) ----
        {
            const unsigned long long m0 = scanm[0], m1 = scanm[1];
            const int st = m0 ? (__ffsll(m0) - 1) : (m1 ? 63 + __ffsll(m1) : -1);
            if (st >= 0) { stopT = st; break; }
        }
        if (c < 8) {
            float s = 0.f;
            #pragma unroll
            for (int w = 0; w < 12; ++w) s += rscr[w][c];
            SD[c] = s;
        }
        // ---- fire-and-forget publish of iteration t-1 (c==0) ----
        if (c == 0) {
            float nb = 0.f, db = 0.f;
            #pragma unroll
            for (int w = 0; w < 12; ++w) { nb += rscr[w][8]; db += rscr[w][9]; }
            __hip_atomic_fetch_add(&den[t], db, __ATOMIC_RELAXED, __HIP_MEMORY_SCOPE_AGENT);
            if (t > 0) {
                __hip_atomic_fetch_add(&num[t - 1], nb, __ATOMIC_RELAXED, __HIP_MEMORY_SCOPE_AGENT);
                __hip_atomic_fetch_add(&arr[t - 1], 1, __ATOMIC_RELEASE, __HIP_MEMORY_SCOPE_AGENT);
            }
        }
        // ---- scan loads (state machine; evaluated in phase 3) ----
        if (c < NITER) {
            if (sstate == 0) {
                aval = __hip_atomic_load(&arr[c], __ATOMIC_RELAXED, __HIP_MEMORY_SCOPE_AGENT);
            } else if (sstate == 1) {
                nnv = __hip_atomic_load(&num[c], __ATOMIC_RELAXED, __HIP_MEMORY_SCOPE_AGENT);
                ddv = __hip_atomic_load(&den[c], __ATOMIC_RELAXED, __HIP_MEMORY_SCOPE_AGENT);
            }
        }

        // ---- phase 2: 4 LDS granules + 8 register granules, zero streamed ----
        float4 acc0 = make_float4(0.f,0.f,0.f,0.f);
        float4 acc1 = make_float4(0.f,0.f,0.f,0.f);
        float4 acc2 = make_float4(0.f,0.f,0.f,0.f);
        float4 acc3 = make_float4(0.f,0.f,0.f,0.f);
        {
            { uint4 r0,r1; KRES(r0,r1, 0); GFMA(r0,r1, 0); }
            { uint4 r0,r1; KRES(r0,r1, 1); GFMA(r0,r1, 1); }
            { uint4 r0,r1; KRES(r0,r1, 2); GFMA(r0,r1, 2); }
            { uint4 r0,r1; KRES(r0,r1, 3); GFMA(r0,r1, 3); }
            GFMA(p40,p41, 4);
            GFMA(p50,p51, 5);
            GFMA(p60,p61, 6);
            GFMA(p70,p71, 7);
            GFMA(p80,p81, 8);
            GFMA(p90,p91, 9);
            GFMA(pA0,pA1, 10);
            GFMA(pB0,pB1, 11);
        }
        *reinterpret_cast<float4*>(&wpart[(o * RPB + 0) * BSZ + 4*u]) = acc0;
        *reinterpret_cast<float4*>(&wpart[(o * RPB + 1) * BSZ + 4*u]) = acc1;
        *reinterpret_cast<float4*>(&wpart[(o * RPB + 2) * BSZ + 4*u]) = acc2;
        *reinterpret_cast<float4*>(&wpart[(o * RPB + 3) * BSZ + 4*u]) = acc3;
        __syncthreads();   // B2

        // ---- phase 3: step t, prepare t+1, reductions, scan eval ----
        float nump = 0.f, an2 = 0.f;
        float zn[RPB] = {0.f, 0.f, 0.f, 0.f};
        float anA[RPB] = {0.f, 0.f, 0.f, 0.f};
        if (act) {
            const float beta1 = (float)(t + 1) / ((float)(t + 1) + 3.0f);
            #pragma unroll
            for (int r = 0; r < RPB; ++r) {
                float w = 0.f;
                #pragma unroll
                for (int oo = 0; oo < 8; ++oo) w += wpart[(oo * RPB + r) * BSZ + c];
                float an = 0.f;
                if (vld[r]) {
                    const float grad = SD[r] * (1.f - kb[r]) + 0.1f * z[r] + w - SD[4 + r] - 2.0f;
                    an = z[r] - 0.001f * grad;
                    an = fminf(fmaxf(an, 0.f), 1.f);
                }
                const float d = an - a[r];
                nump += d * d;
                an2  += an * an;
                zn[r] = an + beta1 * (an - a[r]);
                anA[r] = an;
                a[r] = an;
            }
            #pragma unroll
            for (int r = 0; r < RPB; ++r) {
                reinterpret_cast<__half*>(&zh[r][0])[c] = __float2half(zn[r]);
                z[r] = zn[r];
            }
        }
        // ---- packed-fp16 register ring update ----
        {
            const int slot = t & (RINGD - 1);
            const __half2 h01 = __floats2half2_rn(anA[0], anA[1]);
            const __half2 h23 = __floats2half2_rn(anA[2], anA[3]);
            const unsigned px = *reinterpret_cast<const unsigned*>(&h01);
            const unsigned py = *reinterpret_cast<const unsigned*>(&h23);
            #pragma unroll
            for (int s2 = 0; s2 < RINGD; ++s2) {
                histx[s2] = (s2 == slot) ? px : histx[s2];
                histy[s2] = (s2 == slot) ? py : histy[s2];
            }
        }
        {
            float vv[10] = { zn[0], zn[1], zn[2], zn[3],
                             kb[0]*zn[0], kb[1]*zn[1], kb[2]*zn[2], kb[3]*zn[3],
                             nump, an2 };
            #pragma unroll
            for (int k = 0; k < 10; ++k) {
                float x = vv[k];
                x += __shfl_down(x, 32, 64); x += __shfl_down(x, 16, 64);
                x += __shfl_down(x,  8, 64); x += __shfl_down(x,  4, 64);
                x += __shfl_down(x,  2, 64); x += __shfl_down(x,  1, 64);
                if (lane == 0) rscr[wv][k] = x;
            }
        }
        // ---- scan state transitions + ballot ----
        if (c < NITER) {
            if (sstate == 0) { if (aval == ARRFULL) sstate = 1; }
            else if (sstate == 1) {
                okv = (sqrtf(nnv) / (sqrtf(ddv) + 1e-8f) < 0.01f) ? 1 : 0;
                sstate = 2;
            }
        }
        {
            const unsigned long long bm = __ballot(okv);
            if (lane == 0 && wv < 2) scanm[wv] = bm;
        }
        __syncthreads();   // B3
    }

    // ---- finalize ----
    float av[RPB];
    #pragma unroll
    for (int r = 0; r < RPB; ++r) av[r] = a[r];
    if (stopT >= 0) {
        unsigned sx = histx[0], sy = histy[0];
        const int sl = stopT & (RINGD - 1);
        #pragma unroll
        for (int s2 = 0; s2 < RINGD; ++s2) {
            sx = (s2 == sl) ? histx[s2] : sx;
            sy = (s2 == sl) ? histy[s2] : sy;
        }
        const float2 f01 = __half22float2(*reinterpret_cast<const __half2*>(&sx));
        const float2 f23 = __half22float2(*reinterpret_cast<const __half2*>(&sy));
        av[0] = f01.x; av[1] = f01.y; av[2] = f23.x; av[3] = f23.y;
    }
    if (act) {
        #pragma unroll
        for (int r = 0; r < RPB; ++r) {
            const int b = g * RPB + r;
            if (vld[r]) {
                const int i = c - (c > b ? 1 : 0);
                afin[(size_t)b * BM1 + i] = av[r];
            }
        }
    }
}

__global__ void __launch_bounds__(384)
loss_kernel(const float* __restrict__ Km, const float* __restrict__ afin,
            double* lossAcc) {
    const int b    = blockIdx.x;
    const int tid  = threadIdx.x;
    const int lane = tid & 63;
    const int wv   = tid >> 6;
    __shared__ double dscr[6][2];
    double np = 0.0, pp = 0.0;
    if (tid < BM1) {
        const float ay = afin[(size_t)b * BM1 + tid];
        const int   I  = tid + (tid >= b);
        np = (double)ay * (double)Km[(size_t)I * NZTOT + BSZ + b];
        pp = (double)ay * (double)Km[(size_t)b * NZTOT + BSZ + b];
    }
    for (int o = 32; o; o >>= 1) { np += __shfl_down(np, o, 64); pp += __shfl_down(pp, o, 64); }
    if (lane == 0) { dscr[wv][0] = np; dscr[wv][1] = pp; }
    __syncthreads();
    if (tid == 0) {
        double nb = 0.0, pb = 0.0;
        for (int w = 0; w < 6; ++w) { nb += dscr[w][0]; pb += dscr[w][1]; }
        __hip_atomic_fetch_add(&lossAcc[0], nb, __ATOMIC_RELAXED, __HIP_MEMORY_SCOPE_AGENT);
        __hip_atomic_fetch_add(&lossAcc[1], pb, __ATOMIC_RELAXED, __HIP_MEMORY_SCOPE_AGENT);
    }
}

__global__ void fin_kernel(const double* lossAcc, float* out) {
    out[0] = expf((float)(lossAcc[0] / 384.0 - lossAcc[1] / 384.0));
}

extern "C" void kernel_launch(void* const* d_in, const int* in_sizes, int n_in,
                              void* d_out, int out_size, void* d_ws, size_t ws_size,
                              hipStream_t stream) {
    const float* xis        = (const float*)d_in[0];
    const float* xjs        = (const float*)d_in[1];
    const float* alpha_init = (const float*)d_in[2];
    float* ws   = (float*)d_ws;
    float* Z    = ws + OFF_Z;
    float* nrm2 = ws + OFF_NRM;
    float* Km   = ws + OFF_K;
    __half* KP2 = (__half*)(ws + OFF_KH);
    float* afin = ws + OFF_A;
    float* num  = ws + OFF_NUM;
    float* den  = ws + OFF_DEN;
    int*   arr  = (int*)(ws + OFF_ARR);
    double* lossAcc = (double*)(ws + OFF_LOSS);
    float* out  = (float*)d_out;

    hipFuncSetAttribute((const void*)pgd_kernel,
                        hipFuncAttributeMaxDynamicSharedMemorySize, DYNB);

    hipLaunchKernelGGL(init_kernel, dim3(1), dim3(128), 0, stream, num, den, arr, lossAcc);
    hipLaunchKernelGGL(norm_kernel, dim3(NZTOT), dim3(64), 0, stream, xis, xjs, Z, nrm2);
    hipLaunchKernelGGL(k_kernel, dim3(BSZ, 3), dim3(256), 0, stream, Z, nrm2, Km, KP2);
    hipLaunchKernelGGL(pgd_kernel, dim3(NBLK), dim3(TPB), DYNB, stream,
                       Km, KP2, alpha_init, afin, num, den, arr);
    hipLaunchKernelGGL(loss_kernel, dim3(BSZ), dim3(384), 0, stream, Km, afin, lossAcc);
    hipLaunchKernelGGL(fin_kernel, dim3(1), dim3(1), 0, stream, lossAcc, out);
}

// Round 18
// 649.078 us; speedup vs baseline: 4.0697x; 1.1404x over previous
//
#include <hip/hip_runtime.h>
#include <hip/hip_fp16.h>
#include <math.h>

#define BSZ   384
#define BM1   383
#define DIM   256
#define NZTOT 768
#define NBLK  96
#define RPB   4
#define TPB   768
#define NITER 100
#define RINGD 8
#define ARRFULL NBLK
#define KLDSU (16 * 5 * 384)            // u32 count: K-steps 0..4 (J-pairs 0..79)
#define KRESB (KLDSU * 4)               // 122880 B
#define WSHB  (4 * 384 * 4)             // 6144 B
#define DYNB  (KRESB + WSHB)            // 129024 B

// ---- ws layout (float offsets) ----
#define OFF_Z    0          // 768*256
#define OFF_NRM  196608     // 768
#define OFF_K    197376     // 384*768 fp32
#define OFF_KH   492288     // 384*384 fp16 row-pair packed (36864 floats)
#define OFF_A    639744     // 384*383 final alpha
#define OFF_NUM  786816     // NITER (pad 128)
#define OFF_DEN  786944
#define OFF_ARR  787072
#define OFF_LOSS 787200     // 2 doubles

typedef _Float16 half8_t __attribute__((ext_vector_type(8)));
typedef float    f32x4_t __attribute__((ext_vector_type(4)));
__device__ __forceinline__ half8_t u4h8(uint4 v) {
    union { uint4 u; half8_t h; } x; x.u = v; return x.h;
}

__global__ void init_kernel(float* num, float* den, int* arr, double* lossAcc) {
    int t = threadIdx.x;
    if (t < NITER) { num[t] = 0.f; den[t] = 0.f; arr[t] = 0; }
    if (t < 2) lossAcc[t] = 0.0;
}

__global__ void __launch_bounds__(64)
norm_kernel(const float* __restrict__ xis, const float* __restrict__ xjs,
            float* __restrict__ Z, float* __restrict__ nrm2) {
    const int row  = blockIdx.x;
    const int lane = threadIdx.x;
    const float* src = (row < BSZ) ? (xis + (size_t)row * DIM)
                                   : (xjs + (size_t)(row - BSZ) * DIM);
    float4 x = reinterpret_cast<const float4*>(src)[lane];
    float s = x.x*x.x + x.y*x.y + x.z*x.z + x.w*x.w;
    for (int m = 32; m; m >>= 1) s += __shfl_xor(s, m, 64);
    float nrm = sqrtf(s);
    float4 z;
    z.x = x.x / nrm; z.y = x.y / nrm; z.z = x.z / nrm; z.w = x.w / nrm;
    reinterpret_cast<float4*>(Z + (size_t)row * DIM)[lane] = z;
    float s2 = z.x*z.x + z.y*z.y + z.z*z.z + z.w*z.w;
    for (int m = 32; m; m >>= 1) s2 += __shfl_xor(s2, m, 64);
    if (lane == 0) nrm2[row] = s2;
}

__global__ void __launch_bounds__(256)
k_kernel(const float* __restrict__ Z, const float* __restrict__ nrm2,
         float* __restrict__ Km, __half* __restrict__ KP2) {
    const int i = blockIdx.x;
    const int j = blockIdx.y * 256 + threadIdx.x;
    __shared__ float zi[DIM];
    zi[threadIdx.x] = Z[(size_t)i * DIM + threadIdx.x];
    __syncthreads();
    const float4* zr = reinterpret_cast<const float4*>(Z + (size_t)j * DIM);
    float acc = 0.f;
    #pragma unroll 8
    for (int k = 0; k < DIM/4; ++k) {
        float4 v = zr[k];
        acc = fmaf(zi[4*k+0], v.x, acc);
        acc = fmaf(zi[4*k+1], v.y, acc);
        acc = fmaf(zi[4*k+2], v.z, acc);
        acc = fmaf(zi[4*k+3], v.w, acc);
    }
    float sq = nrm2[i] + nrm2[j] - 2.f * acc;
    sq = fmaxf(sq, 0.f);
    const float val = expf(-0.1f * sq);
    Km[(size_t)i * NZTOT + j] = val;
    // row-pair packed: KP2[(i/2)*768 + j*2 + (i&1)]
    if (j < BSZ) KP2[(size_t)(i >> 1) * 768 + j * 2 + (i & 1)] = __float2half(val);
}

// ---- MFMA fragment macros (compile-time s/t; per-lane addressing) ----
// A u32-index: (16*s + kgrp*4 + jj)*384 + (c0 + 16*t + mloc); jj via strided reads
#define LDSFRAG(dst, s, t) do {                                               \
    const unsigned* _b = kresu + (16*(s) + kgrp*4)*384 + (c0 + 16*(t) + mloc);\
    dst.x = _b[0]; dst.y = _b[384]; dst.z = _b[768]; dst.w = _b[1152];        \
} while (0)

#define GFRAG(dst, s, t) do {                                                 \
    const unsigned* _b = kp2u + (size_t)(16*(s) + kgrp*4)*384 + (c0 + 16*(t) + mloc); \
    dst.x = _b[0]; dst.y = _b[384]; dst.z = _b[768]; dst.w = _b[1152];        \
} while (0)

#define BFRAG(dst, s) do {                                                    \
    dst = *reinterpret_cast<const uint4*>(&zh[rB][16*(s) + kgrp*4]);          \
} while (0)

#define STEP_LDS(s) do { uint4 _bf, _a0, _a1;                                 \
    BFRAG(_bf, s); LDSFRAG(_a0, s, 0); LDSFRAG(_a1, s, 1);                    \
    acc0 = __builtin_amdgcn_mfma_f32_16x16x32_f16(u4h8(_a0), u4h8(_bf), acc0, 0, 0, 0); \
    acc1 = __builtin_amdgcn_mfma_f32_16x16x32_f16(u4h8(_a1), u4h8(_bf), acc1, 0, 0, 0); \
} while (0)

#define STEP_REG(s, QA, QB) do { uint4 _bf;                                   \
    BFRAG(_bf, s);                                                            \
    acc0 = __builtin_amdgcn_mfma_f32_16x16x32_f16(u4h8(QA), u4h8(_bf), acc0, 0, 0, 0); \
    acc1 = __builtin_amdgcn_mfma_f32_16x16x32_f16(u4h8(QB), u4h8(_bf), acc1, 0, 0, 0); \
} while (0)

__global__ void __launch_bounds__(TPB, 1)
pgd_kernel(const float* __restrict__ Km, const __half* __restrict__ KP2,
           const float* __restrict__ alpha_init,
           float* __restrict__ afin, float* num, float* den, int* arr) {
    const int g    = blockIdx.x;     // 0..95
    const int c    = threadIdx.x;    // 0..767
    const int lane = c & 63;
    const int wv   = c >> 6;         // 0..11
    const int mloc = lane & 15;      // MFMA m/n lane coordinate
    const int kgrp = lane >> 4;      // MFMA k-group
    const int c0   = 32 * wv;        // this wave's 2 c-tiles cover c0..c0+31
    const int rB   = mloc & 3;       // B-operand row (n>=4 lanes read r&3, discarded)

    extern __shared__ char dynlc[];
    unsigned* const kresu = (unsigned*)dynlc;          // raw KP2 copy, K-steps 0..4
    float* const    wshf  = (float*)(dynlc + KRESB);   // W[4][384]

    __shared__ unsigned zh[RPB][200];   // z as packed half2 row-pairs (192 used)
    __shared__ float  rscr[12][10];     // per-wave: zn0..3, kbzn0..3, nump, an2
    __shared__ float  SD[8];            // S0..3, D0..3
    __shared__ unsigned long long scanm[2];

    const bool act = (c < BSZ);
    const unsigned* const kp2u = (const unsigned*)KP2;

    // ---- per-row init (diagonal thread c==b inert) ----
    float a[RPB], kb[RPB]; bool vld[RPB];
    #pragma unroll
    for (int r = 0; r < RPB; ++r) {
        const int b = g * RPB + r;
        vld[r] = act && (c != b);
        kb[r]  = act ? Km[(size_t)b * NZTOT + c] : 0.f;
        float v = 0.f;
        if (vld[r]) {
            const int i = c - (c > b ? 1 : 0);
            v = alpha_init[(size_t)b * BM1 + i];
            v = fminf(fmaxf(v, 0.f), 1.f);
        }
        a[r] = v;
    }
    float z[RPB];
    #pragma unroll
    for (int r = 0; r < RPB; ++r) z[r] = a[r];

    // ---- packed-fp16 register ring ----
    unsigned histx[RINGD], histy[RINGD];
    {
        const __half2 h01 = __floats2half2_rn(a[0], a[1]);
        const __half2 h23 = __floats2half2_rn(a[2], a[3]);
        const unsigned px = *reinterpret_cast<const unsigned*>(&h01);
        const unsigned py = *reinterpret_cast<const unsigned*>(&h23);
        #pragma unroll
        for (int s = 0; s < RINGD; ++s) { histx[s] = px; histy[s] = py; }
    }

    // ---- prologue: K-steps 0..4 -> LDS (raw copy); 5..8 -> persistent frags ----
    {
        const uint4* s4 = reinterpret_cast<const uint4*>(KP2);
        uint4* d4 = reinterpret_cast<uint4*>(kresu);
        #pragma unroll
        for (int i = 0; i < 10; ++i) d4[c + 768 * i] = s4[c + 768 * i];
    }
    uint4 q50,q51, q60,q61, q70,q71, q80,q81;
    GFRAG(q50, 5, 0); GFRAG(q51, 5, 1);
    GFRAG(q60, 6, 0); GFRAG(q61, 6, 1);
    GFRAG(q70, 7, 0); GFRAG(q71, 7, 1);
    GFRAG(q80, 8, 0); GFRAG(q81, 8, 1);

    // ---- prologue "phase 3" for t=0: z(0)=a, reductions ----
    {
        float an2 = 0.f;
        float vv[10];
        #pragma unroll
        for (int r = 0; r < RPB; ++r) {
            if (act) reinterpret_cast<__half*>(&zh[r][0])[c] = __float2half(z[r]);
            vv[r]     = z[r];
            vv[4 + r] = kb[r] * z[r];
            an2 += a[r] * a[r];
        }
        vv[8] = 0.f; vv[9] = an2;
        #pragma unroll
        for (int k = 0; k < 10; ++k) {
            float x = vv[k];
            x += __shfl_down(x, 32, 64); x += __shfl_down(x, 16, 64);
            x += __shfl_down(x,  8, 64); x += __shfl_down(x,  4, 64);
            x += __shfl_down(x,  2, 64); x += __shfl_down(x,  1, 64);
            if (lane == 0) rscr[wv][k] = x;
        }
        if (c < 2) scanm[c] = 0ULL;
    }
    __syncthreads();

    int stopT = -1;
    int sstate = 0, okv = 0, aval = 0;
    float nnv = 0.f, ddv = 1.f;

    for (int t = 0; t < NITER; ++t) {
        // ---- top: stop decision (from ballots of t-1) ----
        {
            const unsigned long long m0 = scanm[0], m1 = scanm[1];
            const int st = m0 ? (__ffsll(m0) - 1) : (m1 ? 63 + __ffsll(m1) : -1);
            if (st >= 0) { stopT = st; break; }
        }
        if (c < 8) {
            float s = 0.f;
            #pragma unroll
            for (int w = 0; w < 12; ++w) s += rscr[w][c];
            SD[c] = s;
        }
        // ---- fire-and-forget publish of iteration t-1 (c==0) ----
        if (c == 0) {
            float nb = 0.f, db = 0.f;
            #pragma unroll
            for (int w = 0; w < 12; ++w) { nb += rscr[w][8]; db += rscr[w][9]; }
            __hip_atomic_fetch_add(&den[t], db, __ATOMIC_RELAXED, __HIP_MEMORY_SCOPE_AGENT);
            if (t > 0) {
                __hip_atomic_fetch_add(&num[t - 1], nb, __ATOMIC_RELAXED, __HIP_MEMORY_SCOPE_AGENT);
                __hip_atomic_fetch_add(&arr[t - 1], 1, __ATOMIC_RELEASE, __HIP_MEMORY_SCOPE_AGENT);
            }
        }
        // ---- scan loads (state machine; evaluated in phase 3) ----
        if (c < NITER) {
            if (sstate == 0) {
                aval = __hip_atomic_load(&arr[c], __ATOMIC_RELAXED, __HIP_MEMORY_SCOPE_AGENT);
            } else if (sstate == 1) {
                nnv = __hip_atomic_load(&num[c], __ATOMIC_RELAXED, __HIP_MEMORY_SCOPE_AGENT);
                ddv = __hip_atomic_load(&den[c], __ATOMIC_RELAXED, __HIP_MEMORY_SCOPE_AGENT);
            }
        }

        // ---- phase 2: MFMA matvec — 5 LDS + 4 reg + 3 streamed K-steps ----
        f32x4_t acc0 = {0.f, 0.f, 0.f, 0.f};
        f32x4_t acc1 = {0.f, 0.f, 0.f, 0.f};
        {
            uint4 g90,g91, gA0,gA1, gB0,gB1;
            GFRAG(g90,  9, 0); GFRAG(g91,  9, 1);
            GFRAG(gA0, 10, 0); GFRAG(gA1, 10, 1);
            GFRAG(gB0, 11, 0); GFRAG(gB1, 11, 1);
            STEP_LDS(0); STEP_LDS(1); STEP_LDS(2); STEP_LDS(3); STEP_LDS(4);
            STEP_REG(5, q50, q51);
            STEP_REG(6, q60, q61);
            STEP_REG(7, q70, q71);
            STEP_REG(8, q80, q81);
            STEP_REG(9,  g90, g91);
            STEP_REG(10, gA0, gA1);
            STEP_REG(11, gB0, gB1);
        }
        // C/D: lane holds D[m=(kgrp*4+j)][n=mloc]; n<4 lanes own W[r=n][c0+16t+m]
        if (mloc < 4) {
            *reinterpret_cast<f32x4_t*>(&wshf[mloc * 384 + c0 + kgrp * 4])      = acc0;
            *reinterpret_cast<f32x4_t*>(&wshf[mloc * 384 + c0 + 16 + kgrp * 4]) = acc1;
        }
        __syncthreads();   // B2

        // ---- phase 3: step t, prepare t+1, reductions, scan eval ----
        float nump = 0.f, an2 = 0.f;
        float zn[RPB] = {0.f, 0.f, 0.f, 0.f};
        float anA[RPB] = {0.f, 0.f, 0.f, 0.f};
        if (act) {
            const float beta1 = (float)(t + 1) / ((float)(t + 1) + 3.0f);
            #pragma unroll
            for (int r = 0; r < RPB; ++r) {
                const float w = wshf[r * 384 + c];
                float an = 0.f;
                if (vld[r]) {
                    const float grad = SD[r] * (1.f - kb[r]) + 0.1f * z[r] + w - SD[4 + r] - 2.0f;
                    an = z[r] - 0.001f * grad;
                    an = fminf(fmaxf(an, 0.f), 1.f);
                }
                const float d = an - a[r];
                nump += d * d;
                an2  += an * an;
                zn[r] = an + beta1 * (an - a[r]);
                anA[r] = an;
                a[r] = an;
            }
            #pragma unroll
            for (int r = 0; r < RPB; ++r) {
                reinterpret_cast<__half*>(&zh[r][0])[c] = __float2half(zn[r]);
                z[r] = zn[r];
            }
        }
        // ---- packed-fp16 register ring update ----
        {
            const int slot = t & (RINGD - 1);
            const __half2 h01 = __floats2half2_rn(anA[0], anA[1]);
            const __half2 h23 = __floats2half2_rn(anA[2], anA[3]);
            const unsigned px = *reinterpret_cast<const unsigned*>(&h01);
            const unsigned py = *reinterpret_cast<const unsigned*>(&h23);
            #pragma unroll
            for (int s2 = 0; s2 < RINGD; ++s2) {
                histx[s2] = (s2 == slot) ? px : histx[s2];
                histy[s2] = (s2 == slot) ? py : histy[s2];
            }
        }
        {
            float vv[10] = { zn[0], zn[1], zn[2], zn[3],
                             kb[0]*zn[0], kb[1]*zn[1], kb[2]*zn[2], kb[3]*zn[3],
                             nump, an2 };
            #pragma unroll
            for (int k = 0; k < 10; ++k) {
                float x = vv[k];
                x += __shfl_down(x, 32, 64); x += __shfl_down(x, 16, 64);
                x += __shfl_down(x,  8, 64); x += __shfl_down(x,  4, 64);
                x += __shfl_down(x,  2, 64); x += __shfl_down(x,  1, 64);
                if (lane == 0) rscr[wv][k] = x;
            }
        }
        // ---- scan state transitions + ballot ----
        if (c < NITER) {
            if (sstate == 0) { if (aval == ARRFULL) sstate = 1; }
            else if (sstate == 1) {
                okv = (sqrtf(nnv) / (sqrtf(ddv) + 1e-8f) < 0.01f) ? 1 : 0;
                sstate = 2;
            }
        }
        {
            const unsigned long long bm = __ballot(okv);
            if (lane == 0 && wv < 2) scanm[wv] = bm;
        }
        __syncthreads();   // B3
    }

    // ---- finalize ----
    float av[RPB];
    #pragma unroll
    for (int r = 0; r < RPB; ++r) av[r] = a[r];
    if (stopT >= 0) {
        unsigned sx = histx[0], sy = histy[0];
        const int sl = stopT & (RINGD - 1);
        #pragma unroll
        for (int s2 = 0; s2 < RINGD; ++s2) {
            sx = (s2 == sl) ? histx[s2] : sx;
            sy = (s2 == sl) ? histy[s2] : sy;
        }
        const float2 f01 = __half22float2(*reinterpret_cast<const __half2*>(&sx));
        const float2 f23 = __half22float2(*reinterpret_cast<const __half2*>(&sy));
        av[0] = f01.x; av[1] = f01.y; av[2] = f23.x; av[3] = f23.y;
    }
    if (act) {
        #pragma unroll
        for (int r = 0; r < RPB; ++r) {
            const int b = g * RPB + r;
            if (vld[r]) {
                const int i = c - (c > b ? 1 : 0);
                afin[(size_t)b * BM1 + i] = av[r];
            }
        }
    }
}

__global__ void __launch_bounds__(384)
loss_kernel(const float* __restrict__ Km, const float* __restrict__ afin,
            double* lossAcc) {
    const int b    = blockIdx.x;
    const int tid  = threadIdx.x;
    const int lane = tid & 63;
    const int wv   = tid >> 6;
    __shared__ double dscr[6][2];
    double np = 0.0, pp = 0.0;
    if (tid < BM1) {
        const float ay = afin[(size_t)b * BM1 + tid];
        const int   I  = tid + (tid >= b);
        np = (double)ay * (double)Km[(size_t)I * NZTOT + BSZ + b];
        pp = (double)ay * (double)Km[(size_t)b * NZTOT + BSZ + b];
    }
    for (int o = 32; o; o >>= 1) { np += __shfl_down(np, o, 64); pp += __shfl_down(pp, o, 64); }
    if (lane == 0) { dscr[wv][0] = np; dscr[wv][1] = pp; }
    __syncthreads();
    if (tid == 0) {
        double nb = 0.0, pb = 0.0;
        for (int w = 0; w < 6; ++w) { nb += dscr[w][0]; pb += dscr[w][1]; }
        __hip_atomic_fetch_add(&lossAcc[0], nb, __ATOMIC_RELAXED, __HIP_MEMORY_SCOPE_AGENT);
        __hip_atomic_fetch_add(&lossAcc[1], pb, __ATOMIC_RELAXED, __HIP_MEMORY_SCOPE_AGENT);
    }
}

__global__ void fin_kernel(const double* lossAcc, float* out) {
    out[0] = expf((float)(lossAcc[0] / 384.0 - lossAcc[1] / 384.0));
}

extern "C" void kernel_launch(void* const* d_in, const int* in_sizes, int n_in,
                              void* d_out, int out_size, void* d_ws, size_t ws_size,
                              hipStream_t stream) {
    const float* xis        = (const float*)d_in[0];
    const float* xjs        = (const float*)d_in[1];
    const float* alpha_init = (const float*)d_in[2];
    float* ws   = (float*)d_ws;
    float* Z    = ws + OFF_Z;
    float* nrm2 = ws + OFF_NRM;
    float* Km   = ws + OFF_K;
    __half* KP2 = (__half*)(ws + OFF_KH);
    float* afin = ws + OFF_A;
    float* num  = ws + OFF_NUM;
    float* den  = ws + OFF_DEN;
    int*   arr  = (int*)(ws + OFF_ARR);
    double* lossAcc = (double*)(ws + OFF_LOSS);
    float* out  = (float*)d_out;

    hipFuncSetAttribute((const void*)pgd_kernel,
                        hipFuncAttributeMaxDynamicSharedMemorySize, DYNB);

    hipLaunchKernelGGL(init_kernel, dim3(1), dim3(128), 0, stream, num, den, arr, lossAcc);
    hipLaunchKernelGGL(norm_kernel, dim3(NZTOT), dim3(64), 0, stream, xis, xjs, Z, nrm2);
    hipLaunchKernelGGL(k_kernel, dim3(BSZ, 3), dim3(256), 0, stream, Z, nrm2, Km, KP2);
    hipLaunchKernelGGL(pgd_kernel, dim3(NBLK), dim3(TPB), DYNB, stream,
                       Km, KP2, alpha_init, afin, num, den, arr);
    hipLaunchKernelGGL(loss_kernel, dim3(BSZ), dim3(384), 0, stream, Km, afin, lossAcc);
    hipLaunchKernelGGL(fin_kernel, dim3(1), dim3(1), 0, stream, lossAcc, out);
}